// Round 1
// baseline (701.376 us; speedup 1.0000x reference)
//
#include <hip/hip_runtime.h>
#include <hip/hip_bf16.h>
#include <math.h>

#define HMAP 800
#define WMAP 800
#define OHW  120
#define NCH  8
#define NPTS 100000
#define SDIM 32

// r = inv_scale = input/output, matches jax compute_weight_mat kernel_scale
__device__ __forceinline__ float rscale() { return 800.0f / 120.0f; }

// Per-output-index normalization sums (sum of triangle weights over in-range taps),
// identical for H and W dims (both 800 -> 120).
__global__ void k_norm(float* __restrict__ S) {
    int i = blockIdx.x * blockDim.x + threadIdx.x;
    if (i >= OHW) return;
    const float r = rscale();
    float c = ((float)i + 0.5f) * r - 0.5f;
    int lo = (int)ceilf(c - r); if (lo < 0) lo = 0;
    int hi = (int)floorf(c + r); if (hi > HMAP - 1) hi = HMAP - 1;
    float s = 0.f;
    for (int j = lo; j <= hi; ++j)
        s += fmaxf(0.f, 1.f - fabsf(c - (float)j) / r);
    S[i] = s;
}

// processed_spatial: out[c, oy, ox] over rotated map; rotated[yy, xx] = spatial[c, xx, W-1-yy]
__global__ void k_spatial(const float* __restrict__ spatial, const float* __restrict__ S,
                          float* __restrict__ out) {
    int t = blockIdx.x * blockDim.x + threadIdx.x;
    if (t >= NCH * OHW * OHW) return;
    int c   = t / (OHW * OHW);
    int rem = t % (OHW * OHW);
    int oy  = rem / OHW, ox = rem % OHW;

    const float r = rscale();
    float cy = ((float)oy + 0.5f) * r - 0.5f;
    float cx = ((float)ox + 0.5f) * r - 0.5f;
    int y0 = (int)ceilf(cy - r);
    int x0 = (int)ceilf(cx - r);

    float wy[14], wx[14];
#pragma unroll
    for (int k = 0; k < 14; ++k) {
        int j = y0 + k;
        float w = 1.f - fabsf(cy - (float)j) / r;
        wy[k] = (j >= 0 && j < HMAP) ? fmaxf(w, 0.f) : 0.f;
        j = x0 + k;
        w = 1.f - fabsf(cx - (float)j) / r;
        wx[k] = (j >= 0 && j < WMAP) ? fmaxf(w, 0.f) : 0.f;
    }

    const float* sp = spatial + (size_t)c * (HMAP * WMAP);
    float acc = 0.f;
    for (int kx = 0; kx < 14; ++kx) {
        float wxx = wx[kx];
        if (wxx == 0.f) continue;
        int col = x0 + kx;                       // rotated column -> spatial dim-1 index
        const float* colp = sp + (size_t)col * WMAP;
        float accy = 0.f;
        for (int ky = 0; ky < 14; ++ky) {
            float wyy = wy[ky];
            if (wyy == 0.f) continue;
            int row = HMAP - 1 - (y0 + ky);      // rot90 CCW: spatial last-dim index
            float v = colp[row];
            if (isnan(v)) v = 0.f;
            else if (isinf(v)) v = (v > 0.f) ? 0.f : -3.4028234663852886e38f;
            if (v > 255.f) v = 255.f;
            accy = fmaf(wyy, v, accy);
        }
        acc = fmaf(wxx, accy, acc);
    }
    out[t] = acc * (1.0f / 255.0f) / (S[oy] * S[ox]);
}

// scatter_entity: each (point, channel) adds into <=2x2 output cells of channel 8+c
__global__ void k_scatter(const float* __restrict__ emb, const int* __restrict__ loc,
                          const float* __restrict__ S, float* __restrict__ out) {
    int t = blockIdx.x * blockDim.x + threadIdx.x;
    if (t >= NPTS * SDIM) return;
    int n = t >> 5, c = t & 31;
    int x = loc[2 * n + 0], y = loc[2 * n + 1];
    x = min(max(x, 0), WMAP - 1);
    y = min(max(y, 0), HMAP - 1);
    float e = emb[t];                            // emb[n][c], coalesced

    const float r = rscale();
    float uy = ((float)y + 0.5f) / r;
    float ux = ((float)x + 0.5f) / r;
    int iy0 = (int)floorf(uy - 0.5f);
    int ix0 = (int)floorf(ux - 0.5f);

    float* base = out + (size_t)(NCH + c) * (OHW * OHW);
#pragma unroll
    for (int a = 0; a < 2; ++a) {
        int iy = iy0 + a;
        if (iy < 0 || iy >= OHW) continue;
        float cyv = ((float)iy + 0.5f) * r - 0.5f;
        float wy = 1.f - fabsf(cyv - (float)y) / r;
        if (wy <= 0.f) continue;
        wy /= S[iy];
#pragma unroll
        for (int b = 0; b < 2; ++b) {
            int ix = ix0 + b;
            if (ix < 0 || ix >= OHW) continue;
            float cxv = ((float)ix + 0.5f) * r - 0.5f;
            float wx = 1.f - fabsf(cxv - (float)x) / r;
            if (wx <= 0.f) continue;
            wx /= S[ix];
            atomicAdd(base + iy * OHW + ix, e * wy * wx);
        }
    }
}

// scalar MLP: relu(relu(s@w1+b1)@w2+b2) -> out[576000..576003]
__global__ void k_mlp(const float* __restrict__ scalar, const float* __restrict__ w1,
                      const float* __restrict__ b1, const float* __restrict__ w2,
                      const float* __restrict__ b2, float* __restrict__ out) {
    __shared__ float h[32];
    int j = threadIdx.x;
    if (j < 32) {
        float a = b1[j];
        for (int i = 0; i < 8; ++i) a = fmaf(scalar[i], w1[i * 32 + j], a);
        h[j] = fmaxf(a, 0.f);
    }
    __syncthreads();
    if (j < 4) {
        float a = b2[j];
        for (int i = 0; i < 32; ++i) a = fmaf(h[i], w2[i * 4 + j], a);
        out[40 * OHW * OHW + j] = fmaxf(a, 0.f);
    }
}

extern "C" void kernel_launch(void* const* d_in, const int* in_sizes, int n_in,
                              void* d_out, int out_size, void* d_ws, size_t ws_size,
                              hipStream_t stream) {
    const float* spatial = (const float*)d_in[0];
    const float* emb     = (const float*)d_in[1];
    const int*   loc     = (const int*)d_in[2];
    const float* scalar  = (const float*)d_in[3];
    const float* w1      = (const float*)d_in[4];
    const float* b1      = (const float*)d_in[5];
    const float* w2      = (const float*)d_in[6];
    const float* b2      = (const float*)d_in[7];
    float* out = (float*)d_out;
    float* S   = (float*)d_ws;   // 120 floats

    hipMemsetAsync(d_out, 0, (size_t)out_size * sizeof(float), stream);
    k_norm<<<1, 128, 0, stream>>>(S);
    k_spatial<<<(NCH * OHW * OHW + 255) / 256, 256, 0, stream>>>(spatial, S, out);
    k_scatter<<<(NPTS * SDIM + 255) / 256, 256, 0, stream>>>(emb, loc, S, out);
    k_mlp<<<1, 64, 0, stream>>>(scalar, w1, b1, w2, b2, out);
}

// Round 2
// 111.924 us; speedup vs baseline: 6.2665x; 6.2665x over previous
//
#include <hip/hip_runtime.h>
#include <hip/hip_bf16.h>
#include <math.h>

#define HMAP 800
#define WMAP 800
#define OHW  120
#define NCELL (OHW * OHW)
#define NCH  8
#define NPTS 100000
#define SDIM 32

__device__ __forceinline__ float rscale() { return 800.0f / 120.0f; }

__device__ __forceinline__ float clipval(float v) {
    if (isnan(v)) v = 0.f;
    else if (isinf(v)) v = (v > 0.f) ? 0.f : -3.4028234663852886e38f;
    if (v > 255.f) v = 255.f;
    return v;
}

// ---------------- workspace layout (int units) ----------------
// [0)        counts   : 14400 int
// [14400)    offsets  : 14400 int
// [28800)    cursors  : 14400 int
// [43200)    S        : 120 float
// [43328)    entries  : 400000 int2  (800000 ints)
// [843328)   T        : 768000 float  (8 x 800 x 120, layout [c][xx][oy])
#define WS_COUNTS  0
#define WS_OFFSETS 14400
#define WS_CURSORS 28800
#define WS_S       43200
#define WS_ENTRIES 43328
#define WS_T       843328
#define WS_REQ_BYTES ((size_t)(WS_T + NCH * WMAP * OHW) * 4)

// ================= spatial path: separable antialiased resize ==============
// pass Y: T[c][xx][oy] = (1/255/ws) * sum_j wy(oy,j) * clip(spatial[c][xx][799-j])
__global__ void k_resizeY(const float* __restrict__ spatial, float* __restrict__ T,
                          int* __restrict__ counts) {
    if (blockIdx.x < (NCELL + 127) / 128) {
        int i = blockIdx.x * 128 + threadIdx.x;
        if (i < NCELL) counts[i] = 0;
    }
    int c = blockIdx.x / WMAP, xx = blockIdx.x % WMAP;
    __shared__ float row[HMAP];
    const float* rp = spatial + (size_t)c * (HMAP * WMAP) + (size_t)xx * WMAP;
    for (int j = threadIdx.x; j < HMAP; j += 128) row[j] = clipval(rp[j]);
    __syncthreads();
    int oy = threadIdx.x;
    if (oy >= OHW) return;
    const float r = rscale();
    float cy = ((float)oy + 0.5f) * r - 0.5f;
    int y0 = (int)ceilf(cy - r);
    float acc = 0.f, ws = 0.f;
#pragma unroll
    for (int k = 0; k < 14; ++k) {
        int j = y0 + k;
        if (j < 0 || j >= HMAP) continue;
        float w = fmaxf(0.f, 1.f - fabsf(cy - (float)j) / r);
        ws += w;
        acc = fmaf(w, row[HMAP - 1 - j], acc);
    }
    T[((size_t)c * WMAP + xx) * OHW + oy] = acc / (255.f * ws);
}

// pass X: out[c][oy][ox] = (1/ws) * sum_kx wx * T[c][x0+kx][oy]
__global__ void k_resizeX(const float* __restrict__ T, float* __restrict__ out) {
    int c = blockIdx.x / OHW, ox = blockIdx.x % OHW;
    int oy = threadIdx.x;
    if (oy >= OHW) return;
    const float r = rscale();
    float cx = ((float)ox + 0.5f) * r - 0.5f;
    int x0 = (int)ceilf(cx - r);
    float acc = 0.f, ws = 0.f;
#pragma unroll
    for (int k = 0; k < 14; ++k) {
        int j = x0 + k;
        if (j < 0 || j >= WMAP) continue;
        float w = fmaxf(0.f, 1.f - fabsf(cx - (float)j) / r);
        ws += w;
        acc = fmaf(w, T[((size_t)c * WMAP + j) * OHW + oy], acc);
    }
    out[((size_t)c * OHW + oy) * OHW + ox] = acc / ws;
}

// ================= scatter path: bin points then gather ==============
__device__ __forceinline__ void point_cells(int x, int y, int& iy0, int& ix0) {
    const float r = rscale();
    float uy = ((float)y + 0.5f) / r;
    float ux = ((float)x + 0.5f) / r;
    iy0 = (int)floorf(uy - 0.5f);
    ix0 = (int)floorf(ux - 0.5f);
}

__global__ void k_count(const int* __restrict__ loc, int* __restrict__ counts) {
    int n = blockIdx.x * blockDim.x + threadIdx.x;
    if (n >= NPTS) return;
    int x = min(max(loc[2 * n + 0], 0), WMAP - 1);
    int y = min(max(loc[2 * n + 1], 0), HMAP - 1);
    int iy0, ix0;
    point_cells(x, y, iy0, ix0);
#pragma unroll
    for (int a = 0; a < 2; ++a) {
        int iy = iy0 + a;
        if (iy < 0 || iy >= OHW) continue;
#pragma unroll
        for (int b = 0; b < 2; ++b) {
            int ix = ix0 + b;
            if (ix < 0 || ix >= OHW) continue;
            atomicAdd(&counts[iy * OHW + ix], 1);
        }
    }
}

// prefix-sum over 14400 counts -> offsets & cursors; also computes S[120]
__global__ void k_prefix(const int* __restrict__ counts, int* __restrict__ offsets,
                         int* __restrict__ cursors, float* __restrict__ S) {
    __shared__ int part[1024];
    int t = threadIdx.x;
    if (t < OHW) {
        const float r = rscale();
        float c = ((float)t + 0.5f) * r - 0.5f;
        int lo = (int)ceilf(c - r); if (lo < 0) lo = 0;
        int hi = (int)floorf(c + r); if (hi > HMAP - 1) hi = HMAP - 1;
        float s = 0.f;
        for (int j = lo; j <= hi; ++j)
            s += fmaxf(0.f, 1.f - fabsf(c - (float)j) / r);
        S[t] = s;
    }
    const int PER = 15;  // 1024*15 >= 14400
    int base = t * PER;
    int s = 0;
    for (int k = 0; k < PER; ++k) { int i = base + k; if (i < NCELL) s += counts[i]; }
    part[t] = s;
    __syncthreads();
    for (int off = 1; off < 1024; off <<= 1) {
        int v = (t >= off) ? part[t - off] : 0;
        __syncthreads();
        part[t] += v;
        __syncthreads();
    }
    int run = part[t] - s;  // exclusive
    for (int k = 0; k < PER; ++k) {
        int i = base + k;
        if (i < NCELL) { offsets[i] = run; cursors[i] = run; run += counts[i]; }
    }
}

__global__ void k_fill(const int* __restrict__ loc, const float* __restrict__ S,
                       int* __restrict__ cursors, int2* __restrict__ entries) {
    int n = blockIdx.x * blockDim.x + threadIdx.x;
    if (n >= NPTS) return;
    int x = min(max(loc[2 * n + 0], 0), WMAP - 1);
    int y = min(max(loc[2 * n + 1], 0), HMAP - 1);
    int iy0, ix0;
    point_cells(x, y, iy0, ix0);
    const float r = rscale();
#pragma unroll
    for (int a = 0; a < 2; ++a) {
        int iy = iy0 + a;
        if (iy < 0 || iy >= OHW) continue;
        float cyv = ((float)iy + 0.5f) * r - 0.5f;
        float wy = fmaxf(0.f, 1.f - fabsf(cyv - (float)y) / r) / S[iy];
#pragma unroll
        for (int b = 0; b < 2; ++b) {
            int ix = ix0 + b;
            if (ix < 0 || ix >= OHW) continue;
            float cxv = ((float)ix + 0.5f) * r - 0.5f;
            float wx = fmaxf(0.f, 1.f - fabsf(cxv - (float)x) / r) / S[ix];
            int cell = iy * OHW + ix;
            int slot = atomicAdd(&cursors[cell], 1);
            entries[slot] = make_int2(n, (int)__float_as_uint(wy * wx));
        }
    }
}

// one wave per cell; lanes 0..31 = channels, two halves split entry list
__global__ void k_gather(const float* __restrict__ emb, const int* __restrict__ offsets,
                         const int* __restrict__ counts, const int2* __restrict__ entries,
                         float* __restrict__ out) {
    int cell = blockIdx.x * 4 + (threadIdx.x >> 6);
    int lane = threadIdx.x & 63;
    int c = lane & 31, half = lane >> 5;
    int start = offsets[cell], cnt = counts[cell];
    float acc = 0.f;
    for (int i = half; i < cnt; i += 2) {
        int2 e = entries[start + i];
        float w = __uint_as_float((unsigned)e.y);
        acc = fmaf(w, emb[(size_t)e.x * SDIM + c], acc);
    }
    acc += __shfl_down(acc, 32);
    if (half == 0) out[(size_t)(NCH + c) * NCELL + cell] = acc;
}

// ================= scalar MLP ==============
__global__ void k_mlp(const float* __restrict__ scalar, const float* __restrict__ w1,
                      const float* __restrict__ b1, const float* __restrict__ w2,
                      const float* __restrict__ b2, float* __restrict__ out) {
    __shared__ float h[32];
    int j = threadIdx.x;
    if (j < 32) {
        float a = b1[j];
        for (int i = 0; i < 8; ++i) a = fmaf(scalar[i], w1[i * 32 + j], a);
        h[j] = fmaxf(a, 0.f);
    }
    __syncthreads();
    if (j < 4) {
        float a = b2[j];
        for (int i = 0; i < 32; ++i) a = fmaf(h[i], w2[i * 4 + j], a);
        out[(size_t)(NCH + SDIM) * NCELL + j] = fmaxf(a, 0.f);
    }
}

// ================= fallback (round-1) path, used only if ws too small ======
__global__ void k_norm_fb(float* __restrict__ S) {
    int i = blockIdx.x * blockDim.x + threadIdx.x;
    if (i >= OHW) return;
    const float r = rscale();
    float c = ((float)i + 0.5f) * r - 0.5f;
    int lo = (int)ceilf(c - r); if (lo < 0) lo = 0;
    int hi = (int)floorf(c + r); if (hi > HMAP - 1) hi = HMAP - 1;
    float s = 0.f;
    for (int j = lo; j <= hi; ++j)
        s += fmaxf(0.f, 1.f - fabsf(c - (float)j) / r);
    S[i] = s;
}

__global__ void k_spatial_fb(const float* __restrict__ spatial, const float* __restrict__ S,
                             float* __restrict__ out) {
    int t = blockIdx.x * blockDim.x + threadIdx.x;
    if (t >= NCH * NCELL) return;
    int c = t / NCELL, rem = t % NCELL;
    int oy = rem / OHW, ox = rem % OHW;
    const float r = rscale();
    float cy = ((float)oy + 0.5f) * r - 0.5f;
    float cx = ((float)ox + 0.5f) * r - 0.5f;
    int y0 = (int)ceilf(cy - r);
    int x0 = (int)ceilf(cx - r);
    const float* sp = spatial + (size_t)c * (HMAP * WMAP);
    float acc = 0.f;
    for (int kx = 0; kx < 14; ++kx) {
        int col = x0 + kx;
        if (col < 0 || col >= WMAP) continue;
        float wxx = fmaxf(0.f, 1.f - fabsf(cx - (float)col) / r);
        if (wxx == 0.f) continue;
        const float* colp = sp + (size_t)col * WMAP;
        float accy = 0.f;
        for (int ky = 0; ky < 14; ++ky) {
            int j = y0 + ky;
            if (j < 0 || j >= HMAP) continue;
            float wyy = fmaxf(0.f, 1.f - fabsf(cy - (float)j) / r);
            accy = fmaf(wyy, clipval(colp[HMAP - 1 - j]), accy);
        }
        acc = fmaf(wxx, accy, acc);
    }
    out[t] = acc * (1.0f / 255.0f) / (S[oy] * S[ox]);
}

__global__ void k_scatter_fb(const float* __restrict__ emb, const int* __restrict__ loc,
                             const float* __restrict__ S, float* __restrict__ out) {
    int t = blockIdx.x * blockDim.x + threadIdx.x;
    if (t >= NPTS * SDIM) return;
    int n = t >> 5, c = t & 31;
    int x = min(max(loc[2 * n + 0], 0), WMAP - 1);
    int y = min(max(loc[2 * n + 1], 0), HMAP - 1);
    float e = emb[t];
    int iy0, ix0;
    point_cells(x, y, iy0, ix0);
    const float r = rscale();
    float* base = out + (size_t)(NCH + c) * NCELL;
#pragma unroll
    for (int a = 0; a < 2; ++a) {
        int iy = iy0 + a;
        if (iy < 0 || iy >= OHW) continue;
        float cyv = ((float)iy + 0.5f) * r - 0.5f;
        float wy = fmaxf(0.f, 1.f - fabsf(cyv - (float)y) / r) / S[iy];
#pragma unroll
        for (int b = 0; b < 2; ++b) {
            int ix = ix0 + b;
            if (ix < 0 || ix >= OHW) continue;
            float cxv = ((float)ix + 0.5f) * r - 0.5f;
            float wx = fmaxf(0.f, 1.f - fabsf(cxv - (float)x) / r) / S[ix];
            atomicAdd(base + iy * OHW + ix, e * wy * wx);
        }
    }
}

extern "C" void kernel_launch(void* const* d_in, const int* in_sizes, int n_in,
                              void* d_out, int out_size, void* d_ws, size_t ws_size,
                              hipStream_t stream) {
    const float* spatial = (const float*)d_in[0];
    const float* emb     = (const float*)d_in[1];
    const int*   loc     = (const int*)d_in[2];
    const float* scalar  = (const float*)d_in[3];
    const float* w1      = (const float*)d_in[4];
    const float* b1      = (const float*)d_in[5];
    const float* w2      = (const float*)d_in[6];
    const float* b2      = (const float*)d_in[7];
    float* out = (float*)d_out;

    int*   wsi = (int*)d_ws;
    float* wsf = (float*)d_ws;

    if (ws_size >= WS_REQ_BYTES) {
        int*   counts  = wsi + WS_COUNTS;
        int*   offsets = wsi + WS_OFFSETS;
        int*   cursors = wsi + WS_CURSORS;
        float* S       = wsf + WS_S;
        int2*  entries = (int2*)(wsi + WS_ENTRIES);
        float* T       = wsf + WS_T;

        k_resizeY<<<NCH * WMAP, 128, 0, stream>>>(spatial, T, counts);
        k_resizeX<<<NCH * OHW, 128, 0, stream>>>(T, out);
        k_count<<<(NPTS + 255) / 256, 256, 0, stream>>>(loc, counts);
        k_prefix<<<1, 1024, 0, stream>>>(counts, offsets, cursors, S);
        k_fill<<<(NPTS + 255) / 256, 256, 0, stream>>>(loc, S, cursors, entries);
        k_gather<<<NCELL / 4, 256, 0, stream>>>(emb, offsets, counts, entries, out);
        k_mlp<<<1, 64, 0, stream>>>(scalar, w1, b1, w2, b2, out);
    } else {
        float* S = wsf;
        hipMemsetAsync(d_out, 0, (size_t)out_size * sizeof(float), stream);
        k_norm_fb<<<1, 128, 0, stream>>>(S);
        k_spatial_fb<<<(NCH * NCELL + 255) / 256, 256, 0, stream>>>(spatial, S, out);
        k_scatter_fb<<<(NPTS * SDIM + 255) / 256, 256, 0, stream>>>(emb, loc, S, out);
        k_mlp<<<1, 64, 0, stream>>>(scalar, w1, b1, w2, b2, out);
    }
}

// Round 3
// 69.675 us; speedup vs baseline: 10.0664x; 1.6064x over previous
//
#include <hip/hip_runtime.h>
#include <hip/hip_bf16.h>
#include <math.h>

#define HMAP 800
#define WMAP 800
#define OHW  120
#define NCELL (OHW * OHW)
#define NCH  8
#define NPTS 100000
#define SDIM 32
#define CAP  96

__device__ __forceinline__ float rscale() { return 800.0f / 120.0f; }

__device__ __forceinline__ float clipval(float v) {
    if (isnan(v)) v = 0.f;
    else if (isinf(v)) v = (v > 0.f) ? 0.f : -3.4028234663852886e38f;
    if (v > 255.f) v = 255.f;
    return v;
}

// normalization sum for output index i (same for both dims, both 800->120)
__device__ __forceinline__ float norm_sum(int i) {
    const float r = rscale();
    float c = ((float)i + 0.5f) * r - 0.5f;
    int j0 = (int)ceilf(c - r);
    float s = 0.f;
#pragma unroll
    for (int k = 0; k < 14; ++k) {
        int j = j0 + k;
        if (j < 0 || j >= HMAP) continue;
        s += fmaxf(0.f, 1.f - fabsf(c - (float)j) / r);
    }
    return s;
}

// ---------------- workspace layout (int units) ----------------
#define WS_COUNTS  0                       // 14400 int
#define WS_OVF     14400                   // 460800 float
#define WS_ENTRIES 475200                  // 14400*96 int2 = 2764800 int
#define WS_T       3240000                 // 768000 float
#define WS_END     (WS_T + NCH * WMAP * OHW)
#define WS_REQ_BYTES ((size_t)WS_END * 4)

// ===== spatial pass Y: T[c][xx][oy]; also zeros counts + ovf =====
__global__ void k_resizeY(const float* __restrict__ spatial, float* __restrict__ T,
                          int* __restrict__ counts, float* __restrict__ ovf) {
    int tid = blockIdx.x * 128 + threadIdx.x;
    if (tid < NCELL) counts[tid] = 0;
    if (tid < NCELL * SDIM) ovf[tid] = 0.f;

    int c = blockIdx.x / WMAP, xx = blockIdx.x % WMAP;
    __shared__ float row[HMAP];
    const float* rp = spatial + (size_t)c * (HMAP * WMAP) + (size_t)xx * WMAP;
    for (int j = threadIdx.x; j < HMAP; j += 128) row[j] = clipval(rp[j]);
    __syncthreads();
    int oy = threadIdx.x;
    if (oy >= OHW) return;
    const float r = rscale();
    float cy = ((float)oy + 0.5f) * r - 0.5f;
    int y0 = (int)ceilf(cy - r);
    float acc = 0.f, ws = 0.f;
#pragma unroll
    for (int k = 0; k < 14; ++k) {
        int j = y0 + k;
        if (j < 0 || j >= HMAP) continue;
        float w = fmaxf(0.f, 1.f - fabsf(cy - (float)j) / r);
        ws += w;
        acc = fmaf(w, row[HMAP - 1 - j], acc);
    }
    T[((size_t)c * WMAP + xx) * OHW + oy] = acc / (255.f * ws);
}

// ===== spatial pass X (+ fused scalar MLP in the extra block) =====
__global__ void k_resizeX(const float* __restrict__ T, float* __restrict__ out,
                          const float* __restrict__ scalar, const float* __restrict__ w1,
                          const float* __restrict__ b1, const float* __restrict__ w2,
                          const float* __restrict__ b2) {
    __shared__ float sh[32];
    if (blockIdx.x == NCH * OHW) {           // fused MLP
        int j = threadIdx.x;
        if (j < 32) {
            float a = b1[j];
            for (int i = 0; i < 8; ++i) a = fmaf(scalar[i], w1[i * 32 + j], a);
            sh[j] = fmaxf(a, 0.f);
        }
        __syncthreads();
        if (j < 4) {
            float a = b2[j];
            for (int i = 0; i < 32; ++i) a = fmaf(sh[i], w2[i * 4 + j], a);
            out[(size_t)(NCH + SDIM) * NCELL + j] = fmaxf(a, 0.f);
        }
        return;
    }
    int c = blockIdx.x / OHW, ox = blockIdx.x % OHW;
    int oy = threadIdx.x;
    if (oy >= OHW) return;
    const float r = rscale();
    float cx = ((float)ox + 0.5f) * r - 0.5f;
    int x0 = (int)ceilf(cx - r);
    float acc = 0.f, ws = 0.f;
#pragma unroll
    for (int k = 0; k < 14; ++k) {
        int j = x0 + k;
        if (j < 0 || j >= WMAP) continue;
        float w = fmaxf(0.f, 1.f - fabsf(cx - (float)j) / r);
        ws += w;
        acc = fmaf(w, T[((size_t)c * WMAP + j) * OHW + oy], acc);
    }
    out[((size_t)c * OHW + oy) * OHW + ox] = acc / ws;
}

// ===== single-pass binning: counts as atomic cursors, fixed-cap bins =====
__global__ void k_fill(const int* __restrict__ loc, const float* __restrict__ emb,
                       int* __restrict__ counts, int2* __restrict__ entries,
                       float* __restrict__ ovf) {
    int n = blockIdx.x * blockDim.x + threadIdx.x;
    if (n >= NPTS) return;
    int2 xy = ((const int2*)loc)[n];
    int x = min(max(xy.x, 0), WMAP - 1);
    int y = min(max(xy.y, 0), HMAP - 1);
    const float r = rscale();
    int iy0 = (int)floorf(((float)y + 0.5f) / r - 0.5f);
    int ix0 = (int)floorf(((float)x + 0.5f) / r - 0.5f);
#pragma unroll
    for (int a = 0; a < 2; ++a) {
        int iy = iy0 + a;
        if (iy < 0 || iy >= OHW) continue;
        float cyv = ((float)iy + 0.5f) * r - 0.5f;
        float wy = fmaxf(0.f, 1.f - fabsf(cyv - (float)y) / r) / norm_sum(iy);
#pragma unroll
        for (int b = 0; b < 2; ++b) {
            int ix = ix0 + b;
            if (ix < 0 || ix >= OHW) continue;
            float cxv = ((float)ix + 0.5f) * r - 0.5f;
            float wx = fmaxf(0.f, 1.f - fabsf(cxv - (float)x) / r) / norm_sum(ix);
            float w = wy * wx;
            int cell = iy * OHW + ix;
            int slot = atomicAdd(&counts[cell], 1);
            if (slot < CAP) {
                entries[(size_t)cell * CAP + slot] = make_int2(n, (int)__float_as_uint(w));
            } else {                          // rare overflow: accumulate directly
                for (int c = 0; c < SDIM; ++c)
                    atomicAdd(&ovf[(size_t)cell * SDIM + c], w * emb[(size_t)n * SDIM + c]);
            }
        }
    }
}

// ===== gather: one wave per cell; lanes 0..31 channels, halves split entries =====
__global__ void k_gather(const float* __restrict__ emb, const int* __restrict__ counts,
                         const int2* __restrict__ entries, const float* __restrict__ ovf,
                         float* __restrict__ out) {
    int cell = blockIdx.x * 4 + (threadIdx.x >> 6);
    int lane = threadIdx.x & 63;
    int c = lane & 31, half = lane >> 5;
    int craw = counts[cell];
    int cnt = min(craw, CAP);
    const int2* ep = entries + (size_t)cell * CAP;
    float acc = 0.f;
    for (int i = half; i < cnt; i += 2) {
        int2 e = ep[i];
        acc = fmaf(__uint_as_float((unsigned)e.y), emb[(size_t)e.x * SDIM + c], acc);
    }
    acc += __shfl_down(acc, 32);
    if (half == 0) {
        if (craw > CAP) acc += ovf[(size_t)cell * SDIM + c];
        out[(size_t)(NCH + c) * NCELL + cell] = acc;
    }
}

// ================= fallback path (ws too small): round-1 style ==============
__global__ void k_norm_fb(float* __restrict__ S) {
    int i = blockIdx.x * blockDim.x + threadIdx.x;
    if (i < OHW) S[i] = norm_sum(i);
}

__global__ void k_spatial_fb(const float* __restrict__ spatial, const float* __restrict__ S,
                             float* __restrict__ out) {
    int t = blockIdx.x * blockDim.x + threadIdx.x;
    if (t >= NCH * NCELL) return;
    int c = t / NCELL, rem = t % NCELL;
    int oy = rem / OHW, ox = rem % OHW;
    const float r = rscale();
    float cy = ((float)oy + 0.5f) * r - 0.5f;
    float cx = ((float)ox + 0.5f) * r - 0.5f;
    int y0 = (int)ceilf(cy - r);
    int x0 = (int)ceilf(cx - r);
    const float* sp = spatial + (size_t)c * (HMAP * WMAP);
    float acc = 0.f;
    for (int kx = 0; kx < 14; ++kx) {
        int col = x0 + kx;
        if (col < 0 || col >= WMAP) continue;
        float wxx = fmaxf(0.f, 1.f - fabsf(cx - (float)col) / r);
        if (wxx == 0.f) continue;
        const float* colp = sp + (size_t)col * WMAP;
        float accy = 0.f;
        for (int ky = 0; ky < 14; ++ky) {
            int j = y0 + ky;
            if (j < 0 || j >= HMAP) continue;
            float wyy = fmaxf(0.f, 1.f - fabsf(cy - (float)j) / r);
            accy = fmaf(wyy, clipval(colp[HMAP - 1 - j]), accy);
        }
        acc = fmaf(wxx, accy, acc);
    }
    out[t] = acc * (1.0f / 255.0f) / (S[oy] * S[ox]);
}

__global__ void k_scatter_fb(const float* __restrict__ emb, const int* __restrict__ loc,
                             const float* __restrict__ S, float* __restrict__ out) {
    int t = blockIdx.x * blockDim.x + threadIdx.x;
    if (t >= NPTS * SDIM) return;
    int n = t >> 5, c = t & 31;
    int x = min(max(loc[2 * n + 0], 0), WMAP - 1);
    int y = min(max(loc[2 * n + 1], 0), HMAP - 1);
    float e = emb[t];
    const float r = rscale();
    int iy0 = (int)floorf(((float)y + 0.5f) / r - 0.5f);
    int ix0 = (int)floorf(((float)x + 0.5f) / r - 0.5f);
    float* base = out + (size_t)(NCH + c) * NCELL;
#pragma unroll
    for (int a = 0; a < 2; ++a) {
        int iy = iy0 + a;
        if (iy < 0 || iy >= OHW) continue;
        float cyv = ((float)iy + 0.5f) * r - 0.5f;
        float wy = fmaxf(0.f, 1.f - fabsf(cyv - (float)y) / r) / S[iy];
#pragma unroll
        for (int b = 0; b < 2; ++b) {
            int ix = ix0 + b;
            if (ix < 0 || ix >= OHW) continue;
            float cxv = ((float)ix + 0.5f) * r - 0.5f;
            float wx = fmaxf(0.f, 1.f - fabsf(cxv - (float)x) / r) / S[ix];
            atomicAdd(base + iy * OHW + ix, e * wy * wx);
        }
    }
}

__global__ void k_mlp_fb(const float* __restrict__ scalar, const float* __restrict__ w1,
                         const float* __restrict__ b1, const float* __restrict__ w2,
                         const float* __restrict__ b2, float* __restrict__ out) {
    __shared__ float h[32];
    int j = threadIdx.x;
    if (j < 32) {
        float a = b1[j];
        for (int i = 0; i < 8; ++i) a = fmaf(scalar[i], w1[i * 32 + j], a);
        h[j] = fmaxf(a, 0.f);
    }
    __syncthreads();
    if (j < 4) {
        float a = b2[j];
        for (int i = 0; i < 32; ++i) a = fmaf(h[i], w2[i * 4 + j], a);
        out[(size_t)(NCH + SDIM) * NCELL + j] = fmaxf(a, 0.f);
    }
}

extern "C" void kernel_launch(void* const* d_in, const int* in_sizes, int n_in,
                              void* d_out, int out_size, void* d_ws, size_t ws_size,
                              hipStream_t stream) {
    const float* spatial = (const float*)d_in[0];
    const float* emb     = (const float*)d_in[1];
    const int*   loc     = (const int*)d_in[2];
    const float* scalar  = (const float*)d_in[3];
    const float* w1      = (const float*)d_in[4];
    const float* b1      = (const float*)d_in[5];
    const float* w2      = (const float*)d_in[6];
    const float* b2      = (const float*)d_in[7];
    float* out = (float*)d_out;

    int*   wsi = (int*)d_ws;
    float* wsf = (float*)d_ws;

    if (ws_size >= WS_REQ_BYTES) {
        int*   counts  = wsi + WS_COUNTS;
        float* ovf     = wsf + WS_OVF;
        int2*  entries = (int2*)(wsi + WS_ENTRIES);
        float* T       = wsf + WS_T;

        k_resizeY<<<NCH * WMAP, 128, 0, stream>>>(spatial, T, counts, ovf);
        k_resizeX<<<NCH * OHW + 1, 128, 0, stream>>>(T, out, scalar, w1, b1, w2, b2);
        k_fill<<<(NPTS + 255) / 256, 256, 0, stream>>>(loc, emb, counts, entries, ovf);
        k_gather<<<NCELL / 4, 256, 0, stream>>>(emb, counts, entries, ovf, out);
    } else {
        float* S = wsf;
        hipMemsetAsync(d_out, 0, (size_t)out_size * sizeof(float), stream);
        k_norm_fb<<<1, 128, 0, stream>>>(S);
        k_spatial_fb<<<(NCH * NCELL + 255) / 256, 256, 0, stream>>>(spatial, S, out);
        k_scatter_fb<<<(NPTS * SDIM + 255) / 256, 256, 0, stream>>>(emb, loc, S, out);
        k_mlp_fb<<<1, 64, 0, stream>>>(scalar, w1, b1, w2, b2, out);
    }
}

// Round 4
// 66.172 us; speedup vs baseline: 10.5992x; 1.0529x over previous
//
#include <hip/hip_runtime.h>
#include <hip/hip_bf16.h>
#include <math.h>

#define HMAP 800
#define WMAP 800
#define OHW  120
#define NCELL (OHW * OHW)
#define NCH  8
#define NPTS 100000
#define SDIM 32
#define CAP  32
#define NBIN1 121                 // bins per dim: iy0 in [-1,119] -> +1
#define NBINS (NBIN1 * NBIN1)     // 14641

__device__ __forceinline__ float rscale() { return 800.0f / 120.0f; }

__device__ __forceinline__ float clipval(float v) {
    if (isnan(v)) v = 0.f;
    else if (isinf(v)) v = (v > 0.f) ? 0.f : -3.4028234663852886e38f;
    if (v > 255.f) v = 255.f;
    return v;
}

// normalization sum for output index i (same for both dims, both 800->120)
__device__ __forceinline__ float norm_sum(int i) {
    const float r = rscale();
    float c = ((float)i + 0.5f) * r - 0.5f;
    int j0 = (int)ceilf(c - r);
    float s = 0.f;
#pragma unroll
    for (int k = 0; k < 14; ++k) {
        int j = j0 + k;
        if (j < 0 || j >= HMAP) continue;
        s += fmaxf(0.f, 1.f - fabsf(c - (float)j) / r);
    }
    return s;
}

// ---------------- workspace layout (int units) ----------------
#define WS_COUNTS  0                                  // 14641 int (+pad to 14656)
#define WS_OVF     14656                              // 460800 float
#define WS_ENTRIES (WS_OVF + NCELL * SDIM)            // 14641*32 int2
#define WS_T       (WS_ENTRIES + NBINS * CAP * 2)     // 768000 float
#define WS_END     (WS_T + NCH * WMAP * OHW)
#define WS_REQ_BYTES ((size_t)WS_END * 4)
#define WS_ZERO_BYTES ((size_t)WS_ENTRIES * 4)        // counts + ovf

#define FILL_BLOCKS ((NPTS + 127) / 128)              // 782
#define RY_BLOCKS   (NCH * WMAP)                      // 6400
#define GA_BLOCKS   (NCELL / 4)                       // 3600
#define RX_BLOCKS   (NCH * OHW / 2)                   // 480

// ===== K1: point binning (blocks [0,782)) + spatial pass Y (blocks [782,7182)) =====
__global__ void k_phase1(const float* __restrict__ spatial, const int* __restrict__ loc,
                         const float* __restrict__ emb, float* __restrict__ T,
                         int* __restrict__ counts, int2* __restrict__ entries,
                         float* __restrict__ ovf) {
    __shared__ float row[HMAP];
    if (blockIdx.x < FILL_BLOCKS) {
        int n = blockIdx.x * 128 + threadIdx.x;
        if (n >= NPTS) return;
        int2 xy = ((const int2*)loc)[n];
        int x = min(max(xy.x, 0), WMAP - 1);
        int y = min(max(xy.y, 0), HMAP - 1);
        const float r = rscale();
        int iy0 = (int)floorf(((float)y + 0.5f) / r - 0.5f);
        int ix0 = (int)floorf(((float)x + 0.5f) / r - 0.5f);
        int bin = (iy0 + 1) * NBIN1 + (ix0 + 1);
        int slot = atomicAdd(&counts[bin], 1);
        if (slot < CAP) {
            entries[(size_t)bin * CAP + slot] = make_int2(n, (y << 10) | x);
        } else {  // rare overflow: spill whole point into per-cell ovf
#pragma unroll
            for (int a = 0; a < 2; ++a) {
                int iy = iy0 + a;
                if (iy < 0 || iy >= OHW) continue;
                float cyv = ((float)iy + 0.5f) * r - 0.5f;
                float wy = fmaxf(0.f, 1.f - fabsf(cyv - (float)y) / r) / norm_sum(iy);
#pragma unroll
                for (int b = 0; b < 2; ++b) {
                    int ix = ix0 + b;
                    if (ix < 0 || ix >= OHW) continue;
                    float cxv = ((float)ix + 0.5f) * r - 0.5f;
                    float wx = fmaxf(0.f, 1.f - fabsf(cxv - (float)x) / r) / norm_sum(ix);
                    float w = wy * wx;
                    int cell = iy * OHW + ix;
                    for (int c = 0; c < SDIM; ++c)
                        atomicAdd(&ovf[(size_t)cell * SDIM + c],
                                  w * emb[(size_t)n * SDIM + c]);
                }
            }
        }
        return;
    }
    // ---- resize Y: T[c][xx][oy] ----
    int bx = blockIdx.x - FILL_BLOCKS;
    int c = bx / WMAP, xx = bx % WMAP;
    const float* rp = spatial + (size_t)c * (HMAP * WMAP) + (size_t)xx * WMAP;
    for (int j = threadIdx.x; j < HMAP; j += 128) row[j] = clipval(rp[j]);
    __syncthreads();
    int oy = threadIdx.x;
    if (oy >= OHW) return;
    const float r = rscale();
    float cy = ((float)oy + 0.5f) * r - 0.5f;
    int y0 = (int)ceilf(cy - r);
    float acc = 0.f, ws = 0.f;
#pragma unroll
    for (int k = 0; k < 14; ++k) {
        int j = y0 + k;
        if (j < 0 || j >= HMAP) continue;
        float w = fmaxf(0.f, 1.f - fabsf(cy - (float)j) / r);
        ws += w;
        acc = fmaf(w, row[HMAP - 1 - j], acc);
    }
    T[((size_t)c * WMAP + xx) * OHW + oy] = acc / (255.f * ws);
}

// ===== K2: gather (blocks [0,3600)) + resizeX ([3600,4080)) + MLP (4080) =====
__global__ void k_phase2(const float* __restrict__ T, const float* __restrict__ emb,
                         const int* __restrict__ counts, const int2* __restrict__ entries,
                         const float* __restrict__ ovf, float* __restrict__ out,
                         const float* __restrict__ scalar, const float* __restrict__ w1,
                         const float* __restrict__ b1, const float* __restrict__ w2,
                         const float* __restrict__ b2) {
    __shared__ float sh[32];
    int bid = blockIdx.x;
    if (bid < GA_BLOCKS) {
        int t = threadIdx.x;
        int cell = bid * 4 + (t >> 6);
        int lane = t & 63, c = lane & 31, half = lane >> 5;
        int iy = cell / OHW, ix = cell % OHW;
        const float r = rscale();
        float cy = ((float)iy + 0.5f) * r - 0.5f;
        float cx = ((float)ix + 0.5f) * r - 0.5f;
        float Siy = norm_sum(iy), Six = norm_sum(ix);
        int binbase = iy * NBIN1 + ix;
        float acc = 0.f;
        bool anyovf = false;
#pragma unroll
        for (int dy = 0; dy < 2; ++dy) {
#pragma unroll
            for (int dx = 0; dx < 2; ++dx) {
                int bin = binbase + dy * NBIN1 + dx;
                int craw = counts[bin];
                anyovf |= (craw > CAP);
                int cnt = min(craw, CAP);
                const int2* ep = entries + (size_t)bin * CAP;
                for (int i = half; i < cnt; i += 2) {
                    int2 e = ep[i];
                    float y = (float)(e.y >> 10), x = (float)(e.y & 1023);
                    float wy = fmaxf(0.f, 1.f - fabsf(cy - y) / r) / Siy;
                    float wx = fmaxf(0.f, 1.f - fabsf(cx - x) / r) / Six;
                    acc = fmaf(wy * wx, emb[(size_t)e.x * SDIM + c], acc);
                }
            }
        }
        acc += __shfl_down(acc, 32);
        if (half == 0) {
            if (anyovf) acc += ovf[(size_t)cell * SDIM + c];
            out[(size_t)(NCH + c) * NCELL + cell] = acc;
        }
        return;
    }
    if (bid < GA_BLOCKS + RX_BLOCKS) {   // resize X: 2 (c,ox) columns per block
        int col = (bid - GA_BLOCKS) * 2 + (threadIdx.x >> 7);
        int oy = threadIdx.x & 127;
        if (oy >= OHW) return;
        int c = col / OHW, ox = col % OHW;
        const float r = rscale();
        float cx = ((float)ox + 0.5f) * r - 0.5f;
        int x0 = (int)ceilf(cx - r);
        float acc = 0.f, ws = 0.f;
#pragma unroll
        for (int k = 0; k < 14; ++k) {
            int j = x0 + k;
            if (j < 0 || j >= WMAP) continue;
            float w = fmaxf(0.f, 1.f - fabsf(cx - (float)j) / r);
            ws += w;
            acc = fmaf(w, T[((size_t)c * WMAP + j) * OHW + oy], acc);
        }
        out[((size_t)c * OHW + oy) * OHW + ox] = acc / ws;
        return;
    }
    // ---- fused scalar MLP ----
    int j = threadIdx.x;
    if (j < 32) {
        float a = b1[j];
        for (int i = 0; i < 8; ++i) a = fmaf(scalar[i], w1[i * 32 + j], a);
        sh[j] = fmaxf(a, 0.f);
    }
    __syncthreads();
    if (j < 4) {
        float a = b2[j];
        for (int i = 0; i < 32; ++i) a = fmaf(sh[i], w2[i * 4 + j], a);
        out[(size_t)(NCH + SDIM) * NCELL + j] = fmaxf(a, 0.f);
    }
}

// ================= fallback path (ws too small): round-1 style ==============
__global__ void k_norm_fb(float* __restrict__ S) {
    int i = blockIdx.x * blockDim.x + threadIdx.x;
    if (i < OHW) S[i] = norm_sum(i);
}

__global__ void k_spatial_fb(const float* __restrict__ spatial, const float* __restrict__ S,
                             float* __restrict__ out) {
    int t = blockIdx.x * blockDim.x + threadIdx.x;
    if (t >= NCH * NCELL) return;
    int c = t / NCELL, rem = t % NCELL;
    int oy = rem / OHW, ox = rem % OHW;
    const float r = rscale();
    float cy = ((float)oy + 0.5f) * r - 0.5f;
    float cx = ((float)ox + 0.5f) * r - 0.5f;
    int y0 = (int)ceilf(cy - r);
    int x0 = (int)ceilf(cx - r);
    const float* sp = spatial + (size_t)c * (HMAP * WMAP);
    float acc = 0.f;
    for (int kx = 0; kx < 14; ++kx) {
        int col = x0 + kx;
        if (col < 0 || col >= WMAP) continue;
        float wxx = fmaxf(0.f, 1.f - fabsf(cx - (float)col) / r);
        if (wxx == 0.f) continue;
        const float* colp = sp + (size_t)col * WMAP;
        float accy = 0.f;
        for (int ky = 0; ky < 14; ++ky) {
            int j = y0 + ky;
            if (j < 0 || j >= HMAP) continue;
            float wyy = fmaxf(0.f, 1.f - fabsf(cy - (float)j) / r);
            accy = fmaf(wyy, clipval(colp[HMAP - 1 - j]), accy);
        }
        acc = fmaf(wxx, accy, acc);
    }
    out[t] = acc * (1.0f / 255.0f) / (S[oy] * S[ox]);
}

__global__ void k_scatter_fb(const float* __restrict__ emb, const int* __restrict__ loc,
                             const float* __restrict__ S, float* __restrict__ out) {
    int t = blockIdx.x * blockDim.x + threadIdx.x;
    if (t >= NPTS * SDIM) return;
    int n = t >> 5, c = t & 31;
    int x = min(max(loc[2 * n + 0], 0), WMAP - 1);
    int y = min(max(loc[2 * n + 1], 0), HMAP - 1);
    float e = emb[t];
    const float r = rscale();
    int iy0 = (int)floorf(((float)y + 0.5f) / r - 0.5f);
    int ix0 = (int)floorf(((float)x + 0.5f) / r - 0.5f);
    float* base = out + (size_t)(NCH + c) * NCELL;
#pragma unroll
    for (int a = 0; a < 2; ++a) {
        int iy = iy0 + a;
        if (iy < 0 || iy >= OHW) continue;
        float cyv = ((float)iy + 0.5f) * r - 0.5f;
        float wy = fmaxf(0.f, 1.f - fabsf(cyv - (float)y) / r) / S[iy];
#pragma unroll
        for (int b = 0; b < 2; ++b) {
            int ix = ix0 + b;
            if (ix < 0 || ix >= OHW) continue;
            float cxv = ((float)ix + 0.5f) * r - 0.5f;
            float wx = fmaxf(0.f, 1.f - fabsf(cxv - (float)x) / r) / S[ix];
            atomicAdd(base + iy * OHW + ix, e * wy * wx);
        }
    }
}

__global__ void k_mlp_fb(const float* __restrict__ scalar, const float* __restrict__ w1,
                         const float* __restrict__ b1, const float* __restrict__ w2,
                         const float* __restrict__ b2, float* __restrict__ out) {
    __shared__ float h[32];
    int j = threadIdx.x;
    if (j < 32) {
        float a = b1[j];
        for (int i = 0; i < 8; ++i) a = fmaf(scalar[i], w1[i * 32 + j], a);
        h[j] = fmaxf(a, 0.f);
    }
    __syncthreads();
    if (j < 4) {
        float a = b2[j];
        for (int i = 0; i < 32; ++i) a = fmaf(h[i], w2[i * 4 + j], a);
        out[(size_t)(NCH + SDIM) * NCELL + j] = fmaxf(a, 0.f);
    }
}

extern "C" void kernel_launch(void* const* d_in, const int* in_sizes, int n_in,
                              void* d_out, int out_size, void* d_ws, size_t ws_size,
                              hipStream_t stream) {
    const float* spatial = (const float*)d_in[0];
    const float* emb     = (const float*)d_in[1];
    const int*   loc     = (const int*)d_in[2];
    const float* scalar  = (const float*)d_in[3];
    const float* w1      = (const float*)d_in[4];
    const float* b1      = (const float*)d_in[5];
    const float* w2      = (const float*)d_in[6];
    const float* b2      = (const float*)d_in[7];
    float* out = (float*)d_out;

    int*   wsi = (int*)d_ws;
    float* wsf = (float*)d_ws;

    if (ws_size >= WS_REQ_BYTES) {
        int*   counts  = wsi + WS_COUNTS;
        float* ovf     = wsf + WS_OVF;
        int2*  entries = (int2*)(wsi + WS_ENTRIES);
        float* T       = wsf + WS_T;

        hipMemsetAsync(counts, 0, WS_ZERO_BYTES, stream);
        k_phase1<<<FILL_BLOCKS + RY_BLOCKS, 128, 0, stream>>>(spatial, loc, emb, T,
                                                              counts, entries, ovf);
        k_phase2<<<GA_BLOCKS + RX_BLOCKS + 1, 256, 0, stream>>>(T, emb, counts, entries,
                                                                ovf, out, scalar, w1, b1,
                                                                w2, b2);
    } else {
        float* S = wsf;
        hipMemsetAsync(d_out, 0, (size_t)out_size * sizeof(float), stream);
        k_norm_fb<<<1, 128, 0, stream>>>(S);
        k_spatial_fb<<<(NCH * NCELL + 255) / 256, 256, 0, stream>>>(spatial, S, out);
        k_scatter_fb<<<(NPTS * SDIM + 255) / 256, 256, 0, stream>>>(emb, loc, S, out);
        k_mlp_fb<<<1, 64, 0, stream>>>(scalar, w1, b1, w2, b2, out);
    }
}

// Round 5
// 44.485 us; speedup vs baseline: 15.7667x; 1.4875x over previous
//
#include <hip/hip_runtime.h>
#include <hip/hip_bf16.h>
#include <math.h>

#define HMAP 800
#define WMAP 800
#define OHW  120
#define NCELL (OHW * OHW)
#define NCH  8
#define NPTS 100000
#define SDIM 32
#define CAP  32
#define NBIN1 121                 // bins per dim: iy0 in [-1,119] -> +1
#define NBINS (NBIN1 * NBIN1)     // 14641

__device__ __forceinline__ float rscale() { return 800.0f / 120.0f; }

__device__ __forceinline__ float clipval(float v) {
    if (isnan(v)) v = 0.f;
    else if (isinf(v)) v = (v > 0.f) ? 0.f : -3.4028234663852886e38f;
    if (v > 255.f) v = 255.f;
    return v;
}

// normalization sum for output index i (same for both dims, both 800->120)
__device__ __forceinline__ float norm_sum(int i) {
    const float r = rscale();
    float c = ((float)i + 0.5f) * r - 0.5f;
    int j0 = (int)ceilf(c - r);
    float s = 0.f;
#pragma unroll
    for (int k = 0; k < 14; ++k) {
        int j = j0 + k;
        if (j < 0 || j >= HMAP) continue;
        s += fmaxf(0.f, 1.f - fabsf(c - (float)j) / r);
    }
    return s;
}

// ---------------- workspace layout (int units) ----------------
#define WS_COUNTS  0                                  // 14641 int (+pad to 14656)
#define WS_INVS    14656                              // 128 float
#define WS_OVF     14784                              // 460800 float
#define WS_ENTRIES (WS_OVF + NCELL * SDIM)            // 14641*32 int2
#define WS_T       (WS_ENTRIES + NBINS * CAP * 2)     // 768000 float
#define WS_END     (WS_T + NCH * WMAP * OHW)
#define WS_REQ_BYTES ((size_t)WS_END * 4)
#define WS_ZERO_BYTES ((size_t)WS_ENTRIES * 4)        // counts + invS + ovf

#define FILL_BLOCKS ((NPTS + 127) / 128)              // 782
#define RY_BLOCKS   (NCH * WMAP)                      // 6400
#define GA_BLOCKS   (NCELL / 4)                       // 3600
#define RX_BLOCKS   (NCH * OHW / 2)                   // 480

// ===== K1: point binning (blocks [0,782)) + spatial pass Y (blocks [782,7182)) =====
__global__ void k_phase1(const float* __restrict__ spatial, const int* __restrict__ loc,
                         const float* __restrict__ emb, float* __restrict__ T,
                         int* __restrict__ counts, int2* __restrict__ entries,
                         float* __restrict__ ovf, float* __restrict__ invS) {
    __shared__ float row[HMAP];
    if (blockIdx.x < FILL_BLOCKS) {
        if (blockIdx.x == 0 && threadIdx.x < OHW)
            invS[threadIdx.x] = 1.0f / norm_sum(threadIdx.x);
        int n = blockIdx.x * 128 + threadIdx.x;
        if (n >= NPTS) return;
        int2 xy = ((const int2*)loc)[n];
        int x = min(max(xy.x, 0), WMAP - 1);
        int y = min(max(xy.y, 0), HMAP - 1);
        const float r = rscale();
        int iy0 = (int)floorf(((float)y + 0.5f) / r - 0.5f);
        int ix0 = (int)floorf(((float)x + 0.5f) / r - 0.5f);
        int bin = (iy0 + 1) * NBIN1 + (ix0 + 1);
        int slot = atomicAdd(&counts[bin], 1);
        if (slot < CAP) {
            entries[(size_t)bin * CAP + slot] = make_int2(n, (y << 10) | x);
        } else {  // rare overflow: spill whole point into per-cell ovf
#pragma unroll
            for (int a = 0; a < 2; ++a) {
                int iy = iy0 + a;
                if (iy < 0 || iy >= OHW) continue;
                float cyv = ((float)iy + 0.5f) * r - 0.5f;
                float wy = fmaxf(0.f, 1.f - fabsf(cyv - (float)y) / r) / norm_sum(iy);
#pragma unroll
                for (int b = 0; b < 2; ++b) {
                    int ix = ix0 + b;
                    if (ix < 0 || ix >= OHW) continue;
                    float cxv = ((float)ix + 0.5f) * r - 0.5f;
                    float wx = fmaxf(0.f, 1.f - fabsf(cxv - (float)x) / r) / norm_sum(ix);
                    float w = wy * wx;
                    int cell = iy * OHW + ix;
                    for (int c = 0; c < SDIM; ++c)
                        atomicAdd(&ovf[(size_t)cell * SDIM + c],
                                  w * emb[(size_t)n * SDIM + c]);
                }
            }
        }
        return;
    }
    // ---- resize Y: T[c][xx][oy] ----
    int bx = blockIdx.x - FILL_BLOCKS;
    int c = bx / WMAP, xx = bx % WMAP;
    const float* rp = spatial + (size_t)c * (HMAP * WMAP) + (size_t)xx * WMAP;
    for (int j = threadIdx.x; j < HMAP; j += 128) row[j] = clipval(rp[j]);
    __syncthreads();
    int oy = threadIdx.x;
    if (oy >= OHW) return;
    const float r = rscale();
    const float invR = 1.0f / r;
    float cy = ((float)oy + 0.5f) * r - 0.5f;
    int y0 = (int)ceilf(cy - r);
    float acc = 0.f, ws = 0.f;
#pragma unroll
    for (int k = 0; k < 14; ++k) {
        int j = y0 + k;
        float w = fmaxf(0.f, fmaf(-fabsf(cy - (float)j), invR, 1.f));
        w = (j >= 0 && j < HMAP) ? w : 0.f;           // branchless OOB zero
        int jc = min(max(j, 0), HMAP - 1);
        ws += w;
        acc = fmaf(w, row[HMAP - 1 - jc], acc);
    }
    T[((size_t)c * WMAP + xx) * OHW + oy] = acc / (255.f * ws);
}

// ===== K2: gather (blocks [0,3600)) + resizeX ([3600,4080)) + MLP (4080) =====
__global__ void k_phase2(const float* __restrict__ T, const float* __restrict__ emb,
                         const int* __restrict__ counts, const int2* __restrict__ entries,
                         const float* __restrict__ ovf, const float* __restrict__ invS,
                         float* __restrict__ out,
                         const float* __restrict__ scalar, const float* __restrict__ w1,
                         const float* __restrict__ b1, const float* __restrict__ w2,
                         const float* __restrict__ b2) {
    __shared__ float sh[32];
    int bid = blockIdx.x;
    if (bid < GA_BLOCKS) {
        int t = threadIdx.x;
        int cell = bid * 4 + (t >> 6);
        int lane = t & 63;
        int g = lane >> 4;            // bin group 0..3  (dy'=g>>1, dx'=g&1)
        int c2 = lane & 15;           // channel pair: channels 2*c2, 2*c2+1
        int iy = cell / OHW, ix = cell % OHW;
        const float r = rscale();
        const float invR = 1.0f / r;
        float cy = ((float)iy + 0.5f) * r - 0.5f;
        float cx = ((float)ix + 0.5f) * r - 0.5f;
        float invS2 = invS[iy] * invS[ix];
        int bin = (iy + (g >> 1)) * NBIN1 + (ix + (g & 1));
        int craw = counts[bin];
        bool ovfany = __any(craw > CAP);
        int cnt = min(craw, CAP);
        const int2* ep = entries + (size_t)bin * CAP;
        const float2* embp = (const float2*)emb;
        float ax = 0.f, ay = 0.f;
        for (int i = 0; i < cnt; ++i) {
            int2 e = ep[i];
            float py = (float)((e.y >> 10) & 1023);
            float px = (float)(e.y & 1023);
            float wy = fmaxf(0.f, fmaf(-fabsf(cy - py), invR, 1.f));
            float wx = fmaxf(0.f, fmaf(-fabsf(cx - px), invR, 1.f));
            float w = wy * wx * invS2;
            float2 v = embp[(size_t)e.x * (SDIM / 2) + c2];
            ax = fmaf(w, v.x, ax);
            ay = fmaf(w, v.y, ay);
        }
        ax += __shfl_xor(ax, 16); ay += __shfl_xor(ay, 16);
        ax += __shfl_xor(ax, 32); ay += __shfl_xor(ay, 32);
        if (lane < 16) {
            if (ovfany) {
                ax += ovf[(size_t)cell * SDIM + 2 * c2];
                ay += ovf[(size_t)cell * SDIM + 2 * c2 + 1];
            }
            out[(size_t)(NCH + 2 * c2) * NCELL + cell] = ax;
            out[(size_t)(NCH + 2 * c2 + 1) * NCELL + cell] = ay;
        }
        return;
    }
    if (bid < GA_BLOCKS + RX_BLOCKS) {   // resize X: 2 (c,ox) columns per block
        int col = (bid - GA_BLOCKS) * 2 + (threadIdx.x >> 7);
        int oy = threadIdx.x & 127;
        if (oy >= OHW) return;
        int c = col / OHW, ox = col % OHW;
        const float r = rscale();
        const float invR = 1.0f / r;
        float cx = ((float)ox + 0.5f) * r - 0.5f;
        int x0 = (int)ceilf(cx - r);
        float acc = 0.f, ws = 0.f;
#pragma unroll
        for (int k = 0; k < 14; ++k) {
            int j = x0 + k;
            float w = fmaxf(0.f, fmaf(-fabsf(cx - (float)j), invR, 1.f));
            w = (j >= 0 && j < WMAP) ? w : 0.f;
            int jc = min(max(j, 0), WMAP - 1);
            ws += w;
            acc = fmaf(w, T[((size_t)c * WMAP + jc) * OHW + oy], acc);
        }
        out[((size_t)c * OHW + oy) * OHW + ox] = acc / ws;
        return;
    }
    // ---- fused scalar MLP ----
    int j = threadIdx.x;
    if (j < 32) {
        float a = b1[j];
        for (int i = 0; i < 8; ++i) a = fmaf(scalar[i], w1[i * 32 + j], a);
        sh[j] = fmaxf(a, 0.f);
    }
    __syncthreads();
    if (j < 4) {
        float a = b2[j];
        for (int i = 0; i < 32; ++i) a = fmaf(sh[i], w2[i * 4 + j], a);
        out[(size_t)(NCH + SDIM) * NCELL + j] = fmaxf(a, 0.f);
    }
}

// ================= fallback path (ws too small): round-1 style ==============
__global__ void k_norm_fb(float* __restrict__ S) {
    int i = blockIdx.x * blockDim.x + threadIdx.x;
    if (i < OHW) S[i] = norm_sum(i);
}

__global__ void k_spatial_fb(const float* __restrict__ spatial, const float* __restrict__ S,
                             float* __restrict__ out) {
    int t = blockIdx.x * blockDim.x + threadIdx.x;
    if (t >= NCH * NCELL) return;
    int c = t / NCELL, rem = t % NCELL;
    int oy = rem / OHW, ox = rem % OHW;
    const float r = rscale();
    float cy = ((float)oy + 0.5f) * r - 0.5f;
    float cx = ((float)ox + 0.5f) * r - 0.5f;
    int y0 = (int)ceilf(cy - r);
    int x0 = (int)ceilf(cx - r);
    const float* sp = spatial + (size_t)c * (HMAP * WMAP);
    float acc = 0.f;
    for (int kx = 0; kx < 14; ++kx) {
        int col = x0 + kx;
        if (col < 0 || col >= WMAP) continue;
        float wxx = fmaxf(0.f, 1.f - fabsf(cx - (float)col) / r);
        if (wxx == 0.f) continue;
        const float* colp = sp + (size_t)col * WMAP;
        float accy = 0.f;
        for (int ky = 0; ky < 14; ++ky) {
            int j = y0 + ky;
            if (j < 0 || j >= HMAP) continue;
            float wyy = fmaxf(0.f, 1.f - fabsf(cy - (float)j) / r);
            accy = fmaf(wyy, clipval(colp[HMAP - 1 - j]), accy);
        }
        acc = fmaf(wxx, accy, acc);
    }
    out[t] = acc * (1.0f / 255.0f) / (S[oy] * S[ox]);
}

__global__ void k_scatter_fb(const float* __restrict__ emb, const int* __restrict__ loc,
                             const float* __restrict__ S, float* __restrict__ out) {
    int t = blockIdx.x * blockDim.x + threadIdx.x;
    if (t >= NPTS * SDIM) return;
    int n = t >> 5, c = t & 31;
    int x = min(max(loc[2 * n + 0], 0), WMAP - 1);
    int y = min(max(loc[2 * n + 1], 0), HMAP - 1);
    float e = emb[t];
    const float r = rscale();
    int iy0 = (int)floorf(((float)y + 0.5f) / r - 0.5f);
    int ix0 = (int)floorf(((float)x + 0.5f) / r - 0.5f);
    float* base = out + (size_t)(NCH + c) * NCELL;
#pragma unroll
    for (int a = 0; a < 2; ++a) {
        int iy = iy0 + a;
        if (iy < 0 || iy >= OHW) continue;
        float cyv = ((float)iy + 0.5f) * r - 0.5f;
        float wy = fmaxf(0.f, 1.f - fabsf(cyv - (float)y) / r) / S[iy];
#pragma unroll
        for (int b = 0; b < 2; ++b) {
            int ix = ix0 + b;
            if (ix < 0 || ix >= OHW) continue;
            float cxv = ((float)ix + 0.5f) * r - 0.5f;
            float wx = fmaxf(0.f, 1.f - fabsf(cxv - (float)x) / r) / S[ix];
            atomicAdd(base + iy * OHW + ix, e * wy * wx);
        }
    }
}

__global__ void k_mlp_fb(const float* __restrict__ scalar, const float* __restrict__ w1,
                         const float* __restrict__ b1, const float* __restrict__ w2,
                         const float* __restrict__ b2, float* __restrict__ out) {
    __shared__ float h[32];
    int j = threadIdx.x;
    if (j < 32) {
        float a = b1[j];
        for (int i = 0; i < 8; ++i) a = fmaf(scalar[i], w1[i * 32 + j], a);
        h[j] = fmaxf(a, 0.f);
    }
    __syncthreads();
    if (j < 4) {
        float a = b2[j];
        for (int i = 0; i < 32; ++i) a = fmaf(h[i], w2[i * 4 + j], a);
        out[(size_t)(NCH + SDIM) * NCELL + j] = fmaxf(a, 0.f);
    }
}

extern "C" void kernel_launch(void* const* d_in, const int* in_sizes, int n_in,
                              void* d_out, int out_size, void* d_ws, size_t ws_size,
                              hipStream_t stream) {
    const float* spatial = (const float*)d_in[0];
    const float* emb     = (const float*)d_in[1];
    const int*   loc     = (const int*)d_in[2];
    const float* scalar  = (const float*)d_in[3];
    const float* w1      = (const float*)d_in[4];
    const float* b1      = (const float*)d_in[5];
    const float* w2      = (const float*)d_in[6];
    const float* b2      = (const float*)d_in[7];
    float* out = (float*)d_out;

    int*   wsi = (int*)d_ws;
    float* wsf = (float*)d_ws;

    if (ws_size >= WS_REQ_BYTES) {
        int*   counts  = wsi + WS_COUNTS;
        float* invS    = wsf + WS_INVS;
        float* ovf     = wsf + WS_OVF;
        int2*  entries = (int2*)(wsi + WS_ENTRIES);
        float* T       = wsf + WS_T;

        hipMemsetAsync(counts, 0, WS_ZERO_BYTES, stream);
        k_phase1<<<FILL_BLOCKS + RY_BLOCKS, 128, 0, stream>>>(spatial, loc, emb, T,
                                                              counts, entries, ovf, invS);
        k_phase2<<<GA_BLOCKS + RX_BLOCKS + 1, 256, 0, stream>>>(T, emb, counts, entries,
                                                                ovf, invS, out, scalar,
                                                                w1, b1, w2, b2);
    } else {
        float* S = wsf;
        hipMemsetAsync(d_out, 0, (size_t)out_size * sizeof(float), stream);
        k_norm_fb<<<1, 128, 0, stream>>>(S);
        k_spatial_fb<<<(NCH * NCELL + 255) / 256, 256, 0, stream>>>(spatial, S, out);
        k_scatter_fb<<<(NPTS * SDIM + 255) / 256, 256, 0, stream>>>(emb, loc, S, out);
        k_mlp_fb<<<1, 64, 0, stream>>>(scalar, w1, b1, w2, b2, out);
    }
}

// Round 6
// 43.878 us; speedup vs baseline: 15.9845x; 1.0138x over previous
//
#include <hip/hip_runtime.h>
#include <hip/hip_bf16.h>
#include <math.h>

#define HMAP 800
#define WMAP 800
#define OHW  120
#define NCELL (OHW * OHW)
#define NCH  8
#define NPTS 100000
#define SDIM 32
#define CAP  32
#define NBIN1 121                 // bins per dim: iy0 in [-1,119] -> +1
#define NBINS (NBIN1 * NBIN1)     // 14641

__device__ __forceinline__ float rscale() { return 800.0f / 120.0f; }

__device__ __forceinline__ float clipval(float v) {
    if (isnan(v)) v = 0.f;
    else if (isinf(v)) v = (v > 0.f) ? 0.f : -3.4028234663852886e38f;
    if (v > 255.f) v = 255.f;
    return v;
}

// normalization sum for output index i (same for both dims, both 800->120)
__device__ __forceinline__ float norm_sum(int i) {
    const float r = rscale();
    float c = ((float)i + 0.5f) * r - 0.5f;
    int j0 = (int)ceilf(c - r);
    float s = 0.f;
#pragma unroll
    for (int k = 0; k < 14; ++k) {
        int j = j0 + k;
        if (j < 0 || j >= HMAP) continue;
        s += fmaxf(0.f, 1.f - fabsf(c - (float)j) / r);
    }
    return s;
}

// ---------------- workspace layout (int units) ----------------
#define WS_COUNTS  0                                  // 14641 int (+pad to 14656)
#define WS_INVS    14656                              // 128 float
#define WS_OVF     14784                              // 460800 float
#define WS_ENTRIES (WS_OVF + NCELL * SDIM)            // 14641*32 int2
#define WS_T       (WS_ENTRIES + NBINS * CAP * 2)     // 768000 float
#define WS_END     (WS_T + NCH * WMAP * OHW)
#define WS_REQ_BYTES ((size_t)WS_END * 4)
#define WS_ZERO_INTS ((size_t)WS_ENTRIES)             // counts + invS + ovf (475584 ints)

#define ZERO_BLOCKS ((WS_ZERO_INTS / 4 + 255) / 256)  // float4 per thread -> 465
#define FILL_BLOCKS ((NPTS + 127) / 128)              // 782
#define RY_BLOCKS   (NCH * WMAP)                      // 6400
#define GA_BLOCKS   (NCELL / 4)                       // 3600
#define RX_BLOCKS   (NCH * OHW / 2)                   // 480

// ===== K0: zero counts+invS+ovf (replaces pathologically slow rocclr fillBuffer) =====
__global__ void k_zero(float4* __restrict__ p) {
    size_t i = (size_t)blockIdx.x * 256 + threadIdx.x;
    if (i < WS_ZERO_INTS / 4)
        p[i] = make_float4(0.f, 0.f, 0.f, 0.f);
}

// ===== K1: point binning (blocks [0,782)) + spatial pass Y (blocks [782,7182)) =====
__global__ void k_phase1(const float* __restrict__ spatial, const int* __restrict__ loc,
                         const float* __restrict__ emb, float* __restrict__ T,
                         int* __restrict__ counts, int2* __restrict__ entries,
                         float* __restrict__ ovf, float* __restrict__ invS) {
    __shared__ float row[HMAP];
    if (blockIdx.x < FILL_BLOCKS) {
        if (blockIdx.x == 0 && threadIdx.x < OHW)
            invS[threadIdx.x] = 1.0f / norm_sum(threadIdx.x);
        int n = blockIdx.x * 128 + threadIdx.x;
        if (n >= NPTS) return;
        int2 xy = ((const int2*)loc)[n];
        int x = min(max(xy.x, 0), WMAP - 1);
        int y = min(max(xy.y, 0), HMAP - 1);
        const float r = rscale();
        int iy0 = (int)floorf(((float)y + 0.5f) / r - 0.5f);
        int ix0 = (int)floorf(((float)x + 0.5f) / r - 0.5f);
        int bin = (iy0 + 1) * NBIN1 + (ix0 + 1);
        int slot = atomicAdd(&counts[bin], 1);
        if (slot < CAP) {
            entries[(size_t)bin * CAP + slot] = make_int2(n, (y << 10) | x);
        } else {  // rare overflow: spill whole point into per-cell ovf
#pragma unroll
            for (int a = 0; a < 2; ++a) {
                int iy = iy0 + a;
                if (iy < 0 || iy >= OHW) continue;
                float cyv = ((float)iy + 0.5f) * r - 0.5f;
                float wy = fmaxf(0.f, 1.f - fabsf(cyv - (float)y) / r) / norm_sum(iy);
#pragma unroll
                for (int b = 0; b < 2; ++b) {
                    int ix = ix0 + b;
                    if (ix < 0 || ix >= OHW) continue;
                    float cxv = ((float)ix + 0.5f) * r - 0.5f;
                    float wx = fmaxf(0.f, 1.f - fabsf(cxv - (float)x) / r) / norm_sum(ix);
                    float w = wy * wx;
                    int cell = iy * OHW + ix;
                    for (int c = 0; c < SDIM; ++c)
                        atomicAdd(&ovf[(size_t)cell * SDIM + c],
                                  w * emb[(size_t)n * SDIM + c]);
                }
            }
        }
        return;
    }
    // ---- resize Y: T[c][xx][oy] ----
    int bx = blockIdx.x - FILL_BLOCKS;
    int c = bx / WMAP, xx = bx % WMAP;
    const float* rp = spatial + (size_t)c * (HMAP * WMAP) + (size_t)xx * WMAP;
    for (int j = threadIdx.x; j < HMAP; j += 128) row[j] = clipval(rp[j]);
    __syncthreads();
    int oy = threadIdx.x;
    if (oy >= OHW) return;
    const float r = rscale();
    const float invR = 1.0f / r;
    float cy = ((float)oy + 0.5f) * r - 0.5f;
    int y0 = (int)ceilf(cy - r);
    float acc = 0.f, ws = 0.f;
#pragma unroll
    for (int k = 0; k < 14; ++k) {
        int j = y0 + k;
        float w = fmaxf(0.f, fmaf(-fabsf(cy - (float)j), invR, 1.f));
        w = (j >= 0 && j < HMAP) ? w : 0.f;           // branchless OOB zero
        int jc = min(max(j, 0), HMAP - 1);
        ws += w;
        acc = fmaf(w, row[HMAP - 1 - jc], acc);
    }
    T[((size_t)c * WMAP + xx) * OHW + oy] = acc / (255.f * ws);
}

// ===== K2: gather (blocks [0,3600)) + resizeX ([3600,4080)) + MLP (4080) =====
__global__ void k_phase2(const float* __restrict__ T, const float* __restrict__ emb,
                         const int* __restrict__ counts, const int2* __restrict__ entries,
                         const float* __restrict__ ovf, const float* __restrict__ invS,
                         float* __restrict__ out,
                         const float* __restrict__ scalar, const float* __restrict__ w1,
                         const float* __restrict__ b1, const float* __restrict__ w2,
                         const float* __restrict__ b2) {
    __shared__ float sh[32];
    int bid = blockIdx.x;
    if (bid < GA_BLOCKS) {
        int t = threadIdx.x;
        int cell = bid * 4 + (t >> 6);
        int lane = t & 63;
        int g = lane >> 4;            // bin group 0..3  (dy'=g>>1, dx'=g&1)
        int c2 = lane & 15;           // channel pair: channels 2*c2, 2*c2+1
        int iy = cell / OHW, ix = cell % OHW;
        const float r = rscale();
        const float invR = 1.0f / r;
        float cy = ((float)iy + 0.5f) * r - 0.5f;
        float cx = ((float)ix + 0.5f) * r - 0.5f;
        float invS2 = invS[iy] * invS[ix];
        int bin = (iy + (g >> 1)) * NBIN1 + (ix + (g & 1));
        int craw = counts[bin];
        bool ovfany = __any(craw > CAP);
        int cnt = min(craw, CAP);
        const int2* ep = entries + (size_t)bin * CAP;
        const float2* embp = (const float2*)emb;
        float ax = 0.f, ay = 0.f;
        for (int i = 0; i < cnt; ++i) {
            int2 e = ep[i];
            float py = (float)((e.y >> 10) & 1023);
            float px = (float)(e.y & 1023);
            float wy = fmaxf(0.f, fmaf(-fabsf(cy - py), invR, 1.f));
            float wx = fmaxf(0.f, fmaf(-fabsf(cx - px), invR, 1.f));
            float w = wy * wx * invS2;
            float2 v = embp[(size_t)e.x * (SDIM / 2) + c2];
            ax = fmaf(w, v.x, ax);
            ay = fmaf(w, v.y, ay);
        }
        ax += __shfl_xor(ax, 16); ay += __shfl_xor(ay, 16);
        ax += __shfl_xor(ax, 32); ay += __shfl_xor(ay, 32);
        if (lane < 16) {
            if (ovfany) {
                ax += ovf[(size_t)cell * SDIM + 2 * c2];
                ay += ovf[(size_t)cell * SDIM + 2 * c2 + 1];
            }
            out[(size_t)(NCH + 2 * c2) * NCELL + cell] = ax;
            out[(size_t)(NCH + 2 * c2 + 1) * NCELL + cell] = ay;
        }
        return;
    }
    if (bid < GA_BLOCKS + RX_BLOCKS) {   // resize X: 2 (c,ox) columns per block
        int col = (bid - GA_BLOCKS) * 2 + (threadIdx.x >> 7);
        int oy = threadIdx.x & 127;
        if (oy >= OHW) return;
        int c = col / OHW, ox = col % OHW;
        const float r = rscale();
        const float invR = 1.0f / r;
        float cx = ((float)ox + 0.5f) * r - 0.5f;
        int x0 = (int)ceilf(cx - r);
        float acc = 0.f, ws = 0.f;
#pragma unroll
        for (int k = 0; k < 14; ++k) {
            int j = x0 + k;
            float w = fmaxf(0.f, fmaf(-fabsf(cx - (float)j), invR, 1.f));
            w = (j >= 0 && j < WMAP) ? w : 0.f;
            int jc = min(max(j, 0), WMAP - 1);
            ws += w;
            acc = fmaf(w, T[((size_t)c * WMAP + jc) * OHW + oy], acc);
        }
        out[((size_t)c * OHW + oy) * OHW + ox] = acc / ws;
        return;
    }
    // ---- fused scalar MLP ----
    int j = threadIdx.x;
    if (j < 32) {
        float a = b1[j];
        for (int i = 0; i < 8; ++i) a = fmaf(scalar[i], w1[i * 32 + j], a);
        sh[j] = fmaxf(a, 0.f);
    }
    __syncthreads();
    if (j < 4) {
        float a = b2[j];
        for (int i = 0; i < 32; ++i) a = fmaf(sh[i], w2[i * 4 + j], a);
        out[(size_t)(NCH + SDIM) * NCELL + j] = fmaxf(a, 0.f);
    }
}

// ================= fallback path (ws too small): round-1 style ==============
__global__ void k_norm_fb(float* __restrict__ S) {
    int i = blockIdx.x * blockDim.x + threadIdx.x;
    if (i < OHW) S[i] = norm_sum(i);
}

__global__ void k_spatial_fb(const float* __restrict__ spatial, const float* __restrict__ S,
                             float* __restrict__ out) {
    int t = blockIdx.x * blockDim.x + threadIdx.x;
    if (t >= NCH * NCELL) return;
    int c = t / NCELL, rem = t % NCELL;
    int oy = rem / OHW, ox = rem % OHW;
    const float r = rscale();
    float cy = ((float)oy + 0.5f) * r - 0.5f;
    float cx = ((float)ox + 0.5f) * r - 0.5f;
    int y0 = (int)ceilf(cy - r);
    int x0 = (int)ceilf(cx - r);
    const float* sp = spatial + (size_t)c * (HMAP * WMAP);
    float acc = 0.f;
    for (int kx = 0; kx < 14; ++kx) {
        int col = x0 + kx;
        if (col < 0 || col >= WMAP) continue;
        float wxx = fmaxf(0.f, 1.f - fabsf(cx - (float)col) / r);
        if (wxx == 0.f) continue;
        const float* colp = sp + (size_t)col * WMAP;
        float accy = 0.f;
        for (int ky = 0; ky < 14; ++ky) {
            int j = y0 + ky;
            if (j < 0 || j >= HMAP) continue;
            float wyy = fmaxf(0.f, 1.f - fabsf(cy - (float)j) / r);
            accy = fmaf(wyy, clipval(colp[HMAP - 1 - j]), accy);
        }
        acc = fmaf(wxx, accy, acc);
    }
    out[t] = acc * (1.0f / 255.0f) / (S[oy] * S[ox]);
}

__global__ void k_scatter_fb(const float* __restrict__ emb, const int* __restrict__ loc,
                             const float* __restrict__ S, float* __restrict__ out) {
    int t = blockIdx.x * blockDim.x + threadIdx.x;
    if (t >= NPTS * SDIM) return;
    int n = t >> 5, c = t & 31;
    int x = min(max(loc[2 * n + 0], 0), WMAP - 1);
    int y = min(max(loc[2 * n + 1], 0), HMAP - 1);
    float e = emb[t];
    const float r = rscale();
    int iy0 = (int)floorf(((float)y + 0.5f) / r - 0.5f);
    int ix0 = (int)floorf(((float)x + 0.5f) / r - 0.5f);
    float* base = out + (size_t)(NCH + c) * NCELL;
#pragma unroll
    for (int a = 0; a < 2; ++a) {
        int iy = iy0 + a;
        if (iy < 0 || iy >= OHW) continue;
        float cyv = ((float)iy + 0.5f) * r - 0.5f;
        float wy = fmaxf(0.f, 1.f - fabsf(cyv - (float)y) / r) / S[iy];
#pragma unroll
        for (int b = 0; b < 2; ++b) {
            int ix = ix0 + b;
            if (ix < 0 || ix >= OHW) continue;
            float cxv = ((float)ix + 0.5f) * r - 0.5f;
            float wx = fmaxf(0.f, 1.f - fabsf(cxv - (float)x) / r) / S[ix];
            atomicAdd(base + iy * OHW + ix, e * wy * wx);
        }
    }
}

__global__ void k_mlp_fb(const float* __restrict__ scalar, const float* __restrict__ w1,
                         const float* __restrict__ b1, const float* __restrict__ w2,
                         const float* __restrict__ b2, float* __restrict__ out) {
    __shared__ float h[32];
    int j = threadIdx.x;
    if (j < 32) {
        float a = b1[j];
        for (int i = 0; i < 8; ++i) a = fmaf(scalar[i], w1[i * 32 + j], a);
        h[j] = fmaxf(a, 0.f);
    }
    __syncthreads();
    if (j < 4) {
        float a = b2[j];
        for (int i = 0; i < 32; ++i) a = fmaf(h[i], w2[i * 4 + j], a);
        out[(size_t)(NCH + SDIM) * NCELL + j] = fmaxf(a, 0.f);
    }
}

extern "C" void kernel_launch(void* const* d_in, const int* in_sizes, int n_in,
                              void* d_out, int out_size, void* d_ws, size_t ws_size,
                              hipStream_t stream) {
    const float* spatial = (const float*)d_in[0];
    const float* emb     = (const float*)d_in[1];
    const int*   loc     = (const int*)d_in[2];
    const float* scalar  = (const float*)d_in[3];
    const float* w1      = (const float*)d_in[4];
    const float* b1      = (const float*)d_in[5];
    const float* w2      = (const float*)d_in[6];
    const float* b2      = (const float*)d_in[7];
    float* out = (float*)d_out;

    int*   wsi = (int*)d_ws;
    float* wsf = (float*)d_ws;

    if (ws_size >= WS_REQ_BYTES) {
        int*   counts  = wsi + WS_COUNTS;
        float* invS    = wsf + WS_INVS;
        float* ovf     = wsf + WS_OVF;
        int2*  entries = (int2*)(wsi + WS_ENTRIES);
        float* T       = wsf + WS_T;

        k_zero<<<ZERO_BLOCKS, 256, 0, stream>>>((float4*)d_ws);
        k_phase1<<<FILL_BLOCKS + RY_BLOCKS, 128, 0, stream>>>(spatial, loc, emb, T,
                                                              counts, entries, ovf, invS);
        k_phase2<<<GA_BLOCKS + RX_BLOCKS + 1, 256, 0, stream>>>(T, emb, counts, entries,
                                                                ovf, invS, out, scalar,
                                                                w1, b1, w2, b2);
    } else {
        float* S = wsf;
        hipMemsetAsync(d_out, 0, (size_t)out_size * sizeof(float), stream);
        k_norm_fb<<<1, 128, 0, stream>>>(S);
        k_spatial_fb<<<(NCH * NCELL + 255) / 256, 256, 0, stream>>>(spatial, S, out);
        k_scatter_fb<<<(NPTS * SDIM + 255) / 256, 256, 0, stream>>>(emb, loc, S, out);
        k_mlp_fb<<<1, 64, 0, stream>>>(scalar, w1, b1, w2, b2, out);
    }
}

// Round 7
// 38.102 us; speedup vs baseline: 18.4077x; 1.1516x over previous
//
#include <hip/hip_runtime.h>
#include <hip/hip_bf16.h>
#include <math.h>

#define HMAP 800
#define WMAP 800
#define OHW  120
#define NCELL (OHW * OHW)
#define NCH  8
#define NPTS 100000
#define SDIM 32
#define CAP  32
#define NBIN1 121                 // bins per dim: iy0 in [-1,119] -> +1
#define NBINS (NBIN1 * NBIN1)     // 14641

__device__ __forceinline__ float rscale() { return 800.0f / 120.0f; }

__device__ __forceinline__ float clipval(float v) {
    if (isnan(v)) v = 0.f;
    else if (isinf(v)) v = (v > 0.f) ? 0.f : -3.4028234663852886e38f;
    if (v > 255.f) v = 255.f;
    return v;
}

// normalization sum for output index i (same for both dims, both 800->120)
__device__ __forceinline__ float norm_sum(int i) {
    const float r = rscale();
    float c = ((float)i + 0.5f) * r - 0.5f;
    int j0 = (int)ceilf(c - r);
    float s = 0.f;
#pragma unroll
    for (int k = 0; k < 14; ++k) {
        int j = j0 + k;
        if (j < 0 || j >= HMAP) continue;
        s += fmaxf(0.f, 1.f - fabsf(c - (float)j) / r);
    }
    return s;
}

// ---------------- workspace layout (int units) ----------------
// counts[14641], spill_cursor at [14641], pad to 14656
// invS: 14656 .. 14784 (120 used)
// entries: 14784 .. 14784+937024      (NBINS*CAP int2)
// spill:   951808 .. 1151808          (NPTS int2)
// T:       1151808 .. 1919808         (8*800*120 float)
#define WS_COUNTS   0
#define WS_SPILLCUR 14641
#define WS_INVS     14656
#define WS_ENTRIES  14784
#define WS_SPILL    (WS_ENTRIES + NBINS * CAP * 2)
#define WS_T        (WS_SPILL + NPTS * 2)
#define WS_END      (WS_T + NCH * WMAP * OHW)
#define WS_REQ_BYTES ((size_t)WS_END * 4)

#define ZERO_BLOCKS 58                                // 58*256 >= 14656
#define FILL_BLOCKS ((NPTS + 127) / 128)              // 782
#define RY_BLOCKS   (NCH * WMAP)                      // 6400
#define GA_BLOCKS   (NCELL / 4)                       // 3600
#define RX_BLOCKS   (NCH * OHW / 2)                   // 480

// ===== K0: zero counts+cursor, compute invS table =====
__global__ void k_zero(int* __restrict__ counts, float* __restrict__ invS) {
    int gid = blockIdx.x * 256 + threadIdx.x;
    if (gid < 14656) counts[gid] = 0;
    if (gid < OHW) invS[gid] = 1.0f / norm_sum(gid);
}

// ===== K1: point binning (blocks [0,782)) + spatial pass Y (blocks [782,7182)) =====
__global__ void k_phase1(const float* __restrict__ spatial, const int* __restrict__ loc,
                         float* __restrict__ T, int* __restrict__ counts,
                         int2* __restrict__ entries, int2* __restrict__ spill,
                         int* __restrict__ spill_cur, const float* __restrict__ invS) {
    __shared__ float row[HMAP];
    if (blockIdx.x < FILL_BLOCKS) {
        int n = blockIdx.x * 128 + threadIdx.x;
        if (n >= NPTS) return;
        int2 xy = ((const int2*)loc)[n];
        int x = min(max(xy.x, 0), WMAP - 1);
        int y = min(max(xy.y, 0), HMAP - 1);
        const float r = rscale();
        int iy0 = (int)floorf(((float)y + 0.5f) / r - 0.5f);
        int ix0 = (int)floorf(((float)x + 0.5f) / r - 0.5f);
        int bin = (iy0 + 1) * NBIN1 + (ix0 + 1);
        int pos = (y << 10) | x;
        int slot = atomicAdd(&counts[bin], 1);
        if (slot < CAP) {
            entries[(size_t)bin * CAP + slot] = make_int2(n, pos);
        } else {  // rare overflow: append to spill list (scanned by gather)
            int s = atomicAdd(spill_cur, 1);
            if (s < NPTS) spill[s] = make_int2((bin << 17) | n, pos);
        }
        return;
    }
    // ---- resize Y: T[c][xx][oy] = invS[oy]/255 * sum_j wy * clip(sp[xx][799-j]) ----
    int bx = blockIdx.x - FILL_BLOCKS;
    int c = bx / WMAP, xx = bx % WMAP;
    const float* rp = spatial + (size_t)c * (HMAP * WMAP) + (size_t)xx * WMAP;
    for (int j = threadIdx.x; j < HMAP; j += 128) row[j] = clipval(rp[j]);
    __syncthreads();
    int oy = threadIdx.x;
    if (oy >= OHW) return;
    const float r = rscale();
    const float invR = 1.0f / r;
    float cy = ((float)oy + 0.5f) * r - 0.5f;
    int y0 = (int)ceilf(cy - r);
    float acc = 0.f;
#pragma unroll
    for (int k = 0; k < 14; ++k) {
        int j = y0 + k;
        float w = fmaxf(0.f, fmaf(-fabsf(cy - (float)j), invR, 1.f));
        w = (j >= 0 && j < HMAP) ? w : 0.f;           // branchless OOB zero
        int jc = min(max(j, 0), HMAP - 1);
        acc = fmaf(w, row[HMAP - 1 - jc], acc);
    }
    T[((size_t)c * WMAP + xx) * OHW + oy] = acc * (1.0f / 255.0f) * invS[oy];
}

// ===== K2: gather (blocks [0,3600)) + resizeX ([3600,4080)) + MLP (4080) =====
__global__ void k_phase2(const float* __restrict__ T, const float* __restrict__ emb,
                         const int* __restrict__ counts, const int2* __restrict__ entries,
                         const int2* __restrict__ spill, const int* __restrict__ spill_cur,
                         const float* __restrict__ invS, float* __restrict__ out,
                         const float* __restrict__ scalar, const float* __restrict__ w1,
                         const float* __restrict__ b1, const float* __restrict__ w2,
                         const float* __restrict__ b2) {
    __shared__ int2 st[4][4][CAP];    // [wave][group/bin][slot] = (emb idx, weight bits)
    __shared__ float sh[32];
    int bid = blockIdx.x;
    if (bid < GA_BLOCKS) {
        int t = threadIdx.x;
        int wv = t >> 6;
        int cell = bid * 4 + wv;
        int lane = t & 63;
        int g = lane >> 4;            // bin group 0..3 (dy=g>>1, dx=g&1)
        int c2 = lane & 15;           // channel pair
        int iy = cell / OHW, ix = cell % OHW;
        const float r = rscale();
        const float invR = 1.0f / r;
        float cy = ((float)iy + 0.5f) * r - 0.5f;
        float cx = ((float)ix + 0.5f) * r - 0.5f;
        float invS2 = invS[iy] * invS[ix];
        int b00 = iy * NBIN1 + ix;

        // my main-loop bin
        int mybin = b00 + (g >> 1) * NBIN1 + (g & 1);
        int craw = counts[mybin];
        bool ovfany = __any(craw > CAP);
        int cnt = min(craw, CAP);
        int cmax = cnt;
        cmax = max(cmax, __shfl_xor(cmax, 16));
        cmax = max(cmax, __shfl_xor(cmax, 32));

        // stage: 2 coalesced 512B chunks cover 4 bins x 32 slots; weight precomputed
#pragma unroll
        for (int ch = 0; ch < 2; ++ch) {
            int binrow = b00 + ch * NBIN1;
            const int2* base = entries + (size_t)binrow * CAP;
            int2 e = base[lane];                       // 64 int2 = 512 B coalesced
            int gs = ch * 2 + (lane >> 5);
            int slot = lane & 31;
            int scnt = min(counts[binrow + (lane >> 5)], CAP);
            int idx = 0;
            float w = 0.f;
            if (slot < scnt) {
                float py = (float)((e.y >> 10) & 1023);
                float px = (float)(e.y & 1023);
                float wy = fmaxf(0.f, fmaf(-fabsf(cy - py), invR, 1.f));
                float wx = fmaxf(0.f, fmaf(-fabsf(cx - px), invR, 1.f));
                w = wy * wx * invS2;
                idx = e.x;
            }
            st[wv][gs][slot] = make_int2(idx, __float_as_int(w));
        }
        // wave-local LDS write->read; compiler inserts lgkmcnt waits (no barrier needed)

        const float2* embp = (const float2*)emb;
        float ax = 0.f, ay = 0.f;
        for (int i = 0; i < cmax; i += 4) {           // i+3 <= 31 always
            int2 s0 = st[wv][g][i + 0];
            int2 s1 = st[wv][g][i + 1];
            int2 s2 = st[wv][g][i + 2];
            int2 s3 = st[wv][g][i + 3];
            float2 v0 = embp[(size_t)s0.x * (SDIM / 2) + c2];
            float2 v1 = embp[(size_t)s1.x * (SDIM / 2) + c2];
            float2 v2 = embp[(size_t)s2.x * (SDIM / 2) + c2];
            float2 v3 = embp[(size_t)s3.x * (SDIM / 2) + c2];
            float w0 = __int_as_float(s0.y), w1_ = __int_as_float(s1.y);
            float w2_ = __int_as_float(s2.y), w3 = __int_as_float(s3.y);
            ax = fmaf(w0, v0.x, ax); ay = fmaf(w0, v0.y, ay);
            ax = fmaf(w1_, v1.x, ax); ay = fmaf(w1_, v1.y, ay);
            ax = fmaf(w2_, v2.x, ax); ay = fmaf(w2_, v2.y, ay);
            ax = fmaf(w3, v3.x, ax); ay = fmaf(w3, v3.y, ay);
        }

        if (ovfany) {                                  // rare: scan spill list
            int sn = min(spill_cur[0], NPTS);
            for (int s = 0; s < sn; ++s) {
                int2 e = spill[s];
                if ((e.x >> 17) == mybin) {
                    int n = e.x & 0x1FFFF;
                    float py = (float)((e.y >> 10) & 1023);
                    float px = (float)(e.y & 1023);
                    float wy = fmaxf(0.f, fmaf(-fabsf(cy - py), invR, 1.f));
                    float wx = fmaxf(0.f, fmaf(-fabsf(cx - px), invR, 1.f));
                    float w = wy * wx * invS2;
                    float2 v = embp[(size_t)n * (SDIM / 2) + c2];
                    ax = fmaf(w, v.x, ax); ay = fmaf(w, v.y, ay);
                }
            }
        }

        ax += __shfl_xor(ax, 16); ay += __shfl_xor(ay, 16);
        ax += __shfl_xor(ax, 32); ay += __shfl_xor(ay, 32);
        if (lane < 16) {
            out[(size_t)(NCH + 2 * c2) * NCELL + cell] = ax;
            out[(size_t)(NCH + 2 * c2 + 1) * NCELL + cell] = ay;
        }
        return;
    }
    if (bid < GA_BLOCKS + RX_BLOCKS) {   // resize X: 2 (c,ox) columns per block
        int col = (bid - GA_BLOCKS) * 2 + (threadIdx.x >> 7);
        int oy = threadIdx.x & 127;
        if (oy >= OHW) return;
        int c = col / OHW, ox = col % OHW;
        const float r = rscale();
        const float invR = 1.0f / r;
        float cx = ((float)ox + 0.5f) * r - 0.5f;
        int x0 = (int)ceilf(cx - r);
        float acc = 0.f;
#pragma unroll
        for (int k = 0; k < 14; ++k) {
            int j = x0 + k;
            float w = fmaxf(0.f, fmaf(-fabsf(cx - (float)j), invR, 1.f));
            w = (j >= 0 && j < WMAP) ? w : 0.f;
            int jc = min(max(j, 0), WMAP - 1);
            acc = fmaf(w, T[((size_t)c * WMAP + jc) * OHW + oy], acc);
        }
        out[((size_t)c * OHW + oy) * OHW + ox] = acc * invS[ox];
        return;
    }
    // ---- fused scalar MLP ----
    int j = threadIdx.x;
    if (j < 32) {
        float a = b1[j];
        for (int i = 0; i < 8; ++i) a = fmaf(scalar[i], w1[i * 32 + j], a);
        sh[j] = fmaxf(a, 0.f);
    }
    __syncthreads();
    if (j < 4) {
        float a = b2[j];
        for (int i = 0; i < 32; ++i) a = fmaf(sh[i], w2[i * 4 + j], a);
        out[(size_t)(NCH + SDIM) * NCELL + j] = fmaxf(a, 0.f);
    }
}

// ================= fallback path (ws too small): round-1 style ==============
__global__ void k_norm_fb(float* __restrict__ S) {
    int i = blockIdx.x * blockDim.x + threadIdx.x;
    if (i < OHW) S[i] = norm_sum(i);
}

__global__ void k_spatial_fb(const float* __restrict__ spatial, const float* __restrict__ S,
                             float* __restrict__ out) {
    int t = blockIdx.x * blockDim.x + threadIdx.x;
    if (t >= NCH * NCELL) return;
    int c = t / NCELL, rem = t % NCELL;
    int oy = rem / OHW, ox = rem % OHW;
    const float r = rscale();
    float cy = ((float)oy + 0.5f) * r - 0.5f;
    float cx = ((float)ox + 0.5f) * r - 0.5f;
    int y0 = (int)ceilf(cy - r);
    int x0 = (int)ceilf(cx - r);
    const float* sp = spatial + (size_t)c * (HMAP * WMAP);
    float acc = 0.f;
    for (int kx = 0; kx < 14; ++kx) {
        int col = x0 + kx;
        if (col < 0 || col >= WMAP) continue;
        float wxx = fmaxf(0.f, 1.f - fabsf(cx - (float)col) / r);
        if (wxx == 0.f) continue;
        const float* colp = sp + (size_t)col * WMAP;
        float accy = 0.f;
        for (int ky = 0; ky < 14; ++ky) {
            int j = y0 + ky;
            if (j < 0 || j >= HMAP) continue;
            float wyy = fmaxf(0.f, 1.f - fabsf(cy - (float)j) / r);
            accy = fmaf(wyy, clipval(colp[HMAP - 1 - j]), accy);
        }
        acc = fmaf(wxx, accy, acc);
    }
    out[t] = acc * (1.0f / 255.0f) / (S[oy] * S[ox]);
}

__global__ void k_scatter_fb(const float* __restrict__ emb, const int* __restrict__ loc,
                             const float* __restrict__ S, float* __restrict__ out) {
    int t = blockIdx.x * blockDim.x + threadIdx.x;
    if (t >= NPTS * SDIM) return;
    int n = t >> 5, c = t & 31;
    int x = min(max(loc[2 * n + 0], 0), WMAP - 1);
    int y = min(max(loc[2 * n + 1], 0), HMAP - 1);
    float e = emb[t];
    const float r = rscale();
    int iy0 = (int)floorf(((float)y + 0.5f) / r - 0.5f);
    int ix0 = (int)floorf(((float)x + 0.5f) / r - 0.5f);
    float* base = out + (size_t)(NCH + c) * NCELL;
#pragma unroll
    for (int a = 0; a < 2; ++a) {
        int iy = iy0 + a;
        if (iy < 0 || iy >= OHW) continue;
        float cyv = ((float)iy + 0.5f) * r - 0.5f;
        float wy = fmaxf(0.f, 1.f - fabsf(cyv - (float)y) / r) / S[iy];
#pragma unroll
        for (int b = 0; b < 2; ++b) {
            int ix = ix0 + b;
            if (ix < 0 || ix >= OHW) continue;
            float cxv = ((float)ix + 0.5f) * r - 0.5f;
            float wx = fmaxf(0.f, 1.f - fabsf(cxv - (float)x) / r) / S[ix];
            atomicAdd(base + iy * OHW + ix, e * wy * wx);
        }
    }
}

__global__ void k_mlp_fb(const float* __restrict__ scalar, const float* __restrict__ w1,
                         const float* __restrict__ b1, const float* __restrict__ w2,
                         const float* __restrict__ b2, float* __restrict__ out) {
    __shared__ float h[32];
    int j = threadIdx.x;
    if (j < 32) {
        float a = b1[j];
        for (int i = 0; i < 8; ++i) a = fmaf(scalar[i], w1[i * 32 + j], a);
        h[j] = fmaxf(a, 0.f);
    }
    __syncthreads();
    if (j < 4) {
        float a = b2[j];
        for (int i = 0; i < 32; ++i) a = fmaf(h[i], w2[i * 4 + j], a);
        out[(size_t)(NCH + SDIM) * NCELL + j] = fmaxf(a, 0.f);
    }
}

extern "C" void kernel_launch(void* const* d_in, const int* in_sizes, int n_in,
                              void* d_out, int out_size, void* d_ws, size_t ws_size,
                              hipStream_t stream) {
    const float* spatial = (const float*)d_in[0];
    const float* emb     = (const float*)d_in[1];
    const int*   loc     = (const int*)d_in[2];
    const float* scalar  = (const float*)d_in[3];
    const float* w1      = (const float*)d_in[4];
    const float* b1      = (const float*)d_in[5];
    const float* w2      = (const float*)d_in[6];
    const float* b2      = (const float*)d_in[7];
    float* out = (float*)d_out;

    int*   wsi = (int*)d_ws;
    float* wsf = (float*)d_ws;

    if (ws_size >= WS_REQ_BYTES) {
        int*   counts    = wsi + WS_COUNTS;
        int*   spill_cur = wsi + WS_SPILLCUR;
        float* invS      = wsf + WS_INVS;
        int2*  entries   = (int2*)(wsi + WS_ENTRIES);
        int2*  spill     = (int2*)(wsi + WS_SPILL);
        float* T         = wsf + WS_T;

        k_zero<<<ZERO_BLOCKS, 256, 0, stream>>>(counts, invS);
        k_phase1<<<FILL_BLOCKS + RY_BLOCKS, 128, 0, stream>>>(spatial, loc, T, counts,
                                                              entries, spill, spill_cur,
                                                              invS);
        k_phase2<<<GA_BLOCKS + RX_BLOCKS + 1, 256, 0, stream>>>(T, emb, counts, entries,
                                                                spill, spill_cur, invS,
                                                                out, scalar, w1, b1,
                                                                w2, b2);
    } else {
        float* S = wsf;
        hipMemsetAsync(d_out, 0, (size_t)out_size * sizeof(float), stream);
        k_norm_fb<<<1, 128, 0, stream>>>(S);
        k_spatial_fb<<<(NCH * NCELL + 255) / 256, 256, 0, stream>>>(spatial, S, out);
        k_scatter_fb<<<(NPTS * SDIM + 255) / 256, 256, 0, stream>>>(emb, loc, S, out);
        k_mlp_fb<<<1, 64, 0, stream>>>(scalar, w1, b1, w2, b2, out);
    }
}

// Round 8
// 36.148 us; speedup vs baseline: 19.4028x; 1.0541x over previous
//
#include <hip/hip_runtime.h>
#include <hip/hip_bf16.h>
#include <math.h>

#define HMAP 800
#define WMAP 800
#define OHW  120
#define NCELL (OHW * OHW)
#define NCH  8
#define NPTS 100000
#define SDIM 32
#define CAP  32
#define NBIN1 121                 // bins per dim: iy0 in [-1,119] -> +1
#define NBINS (NBIN1 * NBIN1)     // 14641

__device__ __forceinline__ float rscale() { return 800.0f / 120.0f; }

__device__ __forceinline__ float clipval(float v) {
    if (isnan(v)) v = 0.f;
    else if (isinf(v)) v = (v > 0.f) ? 0.f : -3.4028234663852886e38f;
    if (v > 255.f) v = 255.f;
    return v;
}

// normalization sum for output index i (same for both dims, both 800->120)
__device__ __forceinline__ float norm_sum(int i) {
    const float r = rscale();
    float c = ((float)i + 0.5f) * r - 0.5f;
    int j0 = (int)ceilf(c - r);
    float s = 0.f;
#pragma unroll
    for (int k = 0; k < 14; ++k) {
        int j = j0 + k;
        if (j < 0 || j >= HMAP) continue;
        s += fmaxf(0.f, 1.f - fabsf(c - (float)j) / r);
    }
    return s;
}

// ---------------- workspace layout (int units) ----------------
#define WS_COUNTS   0
#define WS_SPILLCUR 14641
#define WS_INVS     14656
#define WS_ENTRIES  14784
#define WS_SPILL    (WS_ENTRIES + NBINS * CAP * 2)
#define WS_T        (WS_SPILL + NPTS * 2)
#define WS_END      (WS_T + NCH * WMAP * OHW)
#define WS_REQ_BYTES ((size_t)WS_END * 4)

#define ZERO_BLOCKS 58                                // 58*256 >= 14656
#define FILL_BLOCKS ((NPTS + 127) / 128)              // 782
#define RY_BLOCKS   (NCH * WMAP)                      // 6400
#define GA_BLOCKS   (NCELL / 4)                       // 3600 = 8 * 450
#define RX_BLOCKS   (NCH * OHW / 2)                   // 480

// ===== K0: zero counts+cursor, compute invS table =====
__global__ void k_zero(int* __restrict__ counts, float* __restrict__ invS) {
    int gid = blockIdx.x * 256 + threadIdx.x;
    if (gid < 14656) counts[gid] = 0;
    if (gid < OHW) invS[gid] = 1.0f / norm_sum(gid);
}

// ===== K1: point binning (blocks [0,782)) + spatial pass Y (blocks [782,7182)) =====
__global__ void k_phase1(const float* __restrict__ spatial, const int* __restrict__ loc,
                         float* __restrict__ T, int* __restrict__ counts,
                         int2* __restrict__ entries, int2* __restrict__ spill,
                         int* __restrict__ spill_cur, const float* __restrict__ invS) {
    __shared__ float row[HMAP];
    if (blockIdx.x < FILL_BLOCKS) {
        int n = blockIdx.x * 128 + threadIdx.x;
        if (n >= NPTS) return;
        int2 xy = ((const int2*)loc)[n];
        int x = min(max(xy.x, 0), WMAP - 1);
        int y = min(max(xy.y, 0), HMAP - 1);
        const float r = rscale();
        int iy0 = (int)floorf(((float)y + 0.5f) / r - 0.5f);
        int ix0 = (int)floorf(((float)x + 0.5f) / r - 0.5f);
        int bin = (iy0 + 1) * NBIN1 + (ix0 + 1);
        int pos = (y << 10) | x;
        int slot = atomicAdd(&counts[bin], 1);
        if (slot < CAP) {
            entries[(size_t)bin * CAP + slot] = make_int2(n, pos);
        } else {  // rare overflow: append to spill list (scanned by gather)
            int s = atomicAdd(spill_cur, 1);
            if (s < NPTS) spill[s] = make_int2((bin << 17) | n, pos);
        }
        return;
    }
    // ---- resize Y: T[c][xx][oy] = invS[oy]/255 * sum_j wy * clip(sp[xx][799-j]) ----
    int bx = blockIdx.x - FILL_BLOCKS;
    int c = bx / WMAP, xx = bx % WMAP;
    const float* rp = spatial + (size_t)c * (HMAP * WMAP) + (size_t)xx * WMAP;
    for (int j = threadIdx.x; j < HMAP; j += 128) row[j] = clipval(rp[j]);
    __syncthreads();
    int oy = threadIdx.x;
    if (oy >= OHW) return;
    const float r = rscale();
    const float invR = 1.0f / r;
    float cy = ((float)oy + 0.5f) * r - 0.5f;
    int y0 = (int)ceilf(cy - r);
    float acc = 0.f;
#pragma unroll
    for (int k = 0; k < 14; ++k) {
        int j = y0 + k;
        float w = fmaxf(0.f, fmaf(-fabsf(cy - (float)j), invR, 1.f));
        w = (j >= 0 && j < HMAP) ? w : 0.f;           // branchless OOB zero
        int jc = min(max(j, 0), HMAP - 1);
        acc = fmaf(w, row[HMAP - 1 - jc], acc);
    }
    T[((size_t)c * WMAP + xx) * OHW + oy] = acc * (1.0f / 255.0f) * invS[oy];
}

// ===== K2: gather (blocks [0,3600)) + resizeX ([3600,4080)) + MLP (4080) =====
__global__ void k_phase2(const float* __restrict__ T, const float* __restrict__ emb,
                         const int* __restrict__ counts, const int2* __restrict__ entries,
                         const int2* __restrict__ spill, const int* __restrict__ spill_cur,
                         const float* __restrict__ invS, float* __restrict__ out,
                         const float* __restrict__ scalar, const float* __restrict__ w1,
                         const float* __restrict__ b1, const float* __restrict__ w2,
                         const float* __restrict__ b2) {
    __shared__ int2 st[4][4][CAP];    // [wave][group/bin][slot] = (emb idx, weight bits)
    __shared__ float sh[32];
    int bid = blockIdx.x;
    if (bid < GA_BLOCKS) {
        // XCD-aware band swizzle: consecutive hw blocks round-robin XCDs (bid%8);
        // give XCD k the contiguous cell band rows [15k, 15k+15) so the
        // vertical-neighbor bin reuse (30 blocks apart) stays in one XCD's L2.
        int sbid = (bid & 7) * (GA_BLOCKS / 8) + (bid >> 3);   // bijective, 3600=8*450
        int t = threadIdx.x;
        int wv = t >> 6;
        int cell = sbid * 4 + wv;
        int lane = t & 63;
        int g = lane >> 4;            // bin group 0..3 (dy=g>>1, dx=g&1)
        int c2 = lane & 15;           // channel pair
        int iy = cell / OHW, ix = cell % OHW;
        const float r = rscale();
        const float invR = 1.0f / r;
        float cy = ((float)iy + 0.5f) * r - 0.5f;
        float cx = ((float)ix + 0.5f) * r - 0.5f;
        float invS2 = invS[iy] * invS[ix];
        int b00 = iy * NBIN1 + ix;

        // my main-loop bin
        int mybin = b00 + (g >> 1) * NBIN1 + (g & 1);
        int craw = counts[mybin];
        bool ovfany = __any(craw > CAP);
        int cnt = min(craw, CAP);
        int cmax = cnt;
        cmax = max(cmax, __shfl_xor(cmax, 16));
        cmax = max(cmax, __shfl_xor(cmax, 32));

        // stage: 2 coalesced 512B chunks cover 4 bins x 32 slots; weight precomputed
#pragma unroll
        for (int ch = 0; ch < 2; ++ch) {
            int binrow = b00 + ch * NBIN1;
            const int2* base = entries + (size_t)binrow * CAP;
            int2 e = base[lane];                       // 64 int2 = 512 B coalesced
            int gs = ch * 2 + (lane >> 5);
            int slot = lane & 31;
            int scnt = min(counts[binrow + (lane >> 5)], CAP);
            int idx = 0;
            float w = 0.f;
            if (slot < scnt) {
                float py = (float)((e.y >> 10) & 1023);
                float px = (float)(e.y & 1023);
                float wy = fmaxf(0.f, fmaf(-fabsf(cy - py), invR, 1.f));
                float wx = fmaxf(0.f, fmaf(-fabsf(cx - px), invR, 1.f));
                w = wy * wx * invS2;
                idx = e.x;
            }
            st[wv][gs][slot] = make_int2(idx, __float_as_int(w));
        }
        // wave-local LDS write->read; compiler inserts lgkmcnt waits (no barrier needed)

        const float2* embp = (const float2*)emb;
        float ax = 0.f, ay = 0.f;
        for (int i = 0; i < cmax; i += 4) {           // i+3 <= 31 always
            int2 s0 = st[wv][g][i + 0];
            int2 s1 = st[wv][g][i + 1];
            int2 s2 = st[wv][g][i + 2];
            int2 s3 = st[wv][g][i + 3];
            float2 v0 = embp[(size_t)s0.x * (SDIM / 2) + c2];
            float2 v1 = embp[(size_t)s1.x * (SDIM / 2) + c2];
            float2 v2 = embp[(size_t)s2.x * (SDIM / 2) + c2];
            float2 v3 = embp[(size_t)s3.x * (SDIM / 2) + c2];
            float w0 = __int_as_float(s0.y), w1_ = __int_as_float(s1.y);
            float w2_ = __int_as_float(s2.y), w3 = __int_as_float(s3.y);
            ax = fmaf(w0, v0.x, ax); ay = fmaf(w0, v0.y, ay);
            ax = fmaf(w1_, v1.x, ax); ay = fmaf(w1_, v1.y, ay);
            ax = fmaf(w2_, v2.x, ax); ay = fmaf(w2_, v2.y, ay);
            ax = fmaf(w3, v3.x, ax); ay = fmaf(w3, v3.y, ay);
        }

        if (ovfany) {                                  // rare: scan spill list
            int sn = min(spill_cur[0], NPTS);
            for (int s = 0; s < sn; ++s) {
                int2 e = spill[s];
                if ((e.x >> 17) == mybin) {
                    int n = e.x & 0x1FFFF;
                    float py = (float)((e.y >> 10) & 1023);
                    float px = (float)(e.y & 1023);
                    float wy = fmaxf(0.f, fmaf(-fabsf(cy - py), invR, 1.f));
                    float wx = fmaxf(0.f, fmaf(-fabsf(cx - px), invR, 1.f));
                    float w = wy * wx * invS2;
                    float2 v = embp[(size_t)n * (SDIM / 2) + c2];
                    ax = fmaf(w, v.x, ax); ay = fmaf(w, v.y, ay);
                }
            }
        }

        ax += __shfl_xor(ax, 16); ay += __shfl_xor(ay, 16);
        ax += __shfl_xor(ax, 32); ay += __shfl_xor(ay, 32);
        if (lane < 16) {
            out[(size_t)(NCH + 2 * c2) * NCELL + cell] = ax;
            out[(size_t)(NCH + 2 * c2 + 1) * NCELL + cell] = ay;
        }
        return;
    }
    if (bid < GA_BLOCKS + RX_BLOCKS) {   // resize X: 2 (c,ox) columns per block
        int col = (bid - GA_BLOCKS) * 2 + (threadIdx.x >> 7);
        int oy = threadIdx.x & 127;
        if (oy >= OHW) return;
        int c = col / OHW, ox = col % OHW;
        const float r = rscale();
        const float invR = 1.0f / r;
        float cx = ((float)ox + 0.5f) * r - 0.5f;
        int x0 = (int)ceilf(cx - r);
        float acc = 0.f;
#pragma unroll
        for (int k = 0; k < 14; ++k) {
            int j = x0 + k;
            float w = fmaxf(0.f, fmaf(-fabsf(cx - (float)j), invR, 1.f));
            w = (j >= 0 && j < WMAP) ? w : 0.f;
            int jc = min(max(j, 0), WMAP - 1);
            acc = fmaf(w, T[((size_t)c * WMAP + jc) * OHW + oy], acc);
        }
        out[((size_t)c * OHW + oy) * OHW + ox] = acc * invS[ox];
        return;
    }
    // ---- fused scalar MLP ----
    int j = threadIdx.x;
    if (j < 32) {
        float a = b1[j];
        for (int i = 0; i < 8; ++i) a = fmaf(scalar[i], w1[i * 32 + j], a);
        sh[j] = fmaxf(a, 0.f);
    }
    __syncthreads();
    if (j < 4) {
        float a = b2[j];
        for (int i = 0; i < 32; ++i) a = fmaf(sh[i], w2[i * 4 + j], a);
        out[(size_t)(NCH + SDIM) * NCELL + j] = fmaxf(a, 0.f);
    }
}

// ================= fallback path (ws too small): round-1 style ==============
__global__ void k_norm_fb(float* __restrict__ S) {
    int i = blockIdx.x * blockDim.x + threadIdx.x;
    if (i < OHW) S[i] = norm_sum(i);
}

__global__ void k_spatial_fb(const float* __restrict__ spatial, const float* __restrict__ S,
                             float* __restrict__ out) {
    int t = blockIdx.x * blockDim.x + threadIdx.x;
    if (t >= NCH * NCELL) return;
    int c = t / NCELL, rem = t % NCELL;
    int oy = rem / OHW, ox = rem % OHW;
    const float r = rscale();
    float cy = ((float)oy + 0.5f) * r - 0.5f;
    float cx = ((float)ox + 0.5f) * r - 0.5f;
    int y0 = (int)ceilf(cy - r);
    int x0 = (int)ceilf(cx - r);
    const float* sp = spatial + (size_t)c * (HMAP * WMAP);
    float acc = 0.f;
    for (int kx = 0; kx < 14; ++kx) {
        int col = x0 + kx;
        if (col < 0 || col >= WMAP) continue;
        float wxx = fmaxf(0.f, 1.f - fabsf(cx - (float)col) / r);
        if (wxx == 0.f) continue;
        const float* colp = sp + (size_t)col * WMAP;
        float accy = 0.f;
        for (int ky = 0; ky < 14; ++ky) {
            int j = y0 + ky;
            if (j < 0 || j >= HMAP) continue;
            float wyy = fmaxf(0.f, 1.f - fabsf(cy - (float)j) / r);
            accy = fmaf(wyy, clipval(colp[HMAP - 1 - j]), accy);
        }
        acc = fmaf(wxx, accy, acc);
    }
    out[t] = acc * (1.0f / 255.0f) / (S[oy] * S[ox]);
}

__global__ void k_scatter_fb(const float* __restrict__ emb, const int* __restrict__ loc,
                             const float* __restrict__ S, float* __restrict__ out) {
    int t = blockIdx.x * blockDim.x + threadIdx.x;
    if (t >= NPTS * SDIM) return;
    int n = t >> 5, c = t & 31;
    int x = min(max(loc[2 * n + 0], 0), WMAP - 1);
    int y = min(max(loc[2 * n + 1], 0), HMAP - 1);
    float e = emb[t];
    const float r = rscale();
    int iy0 = (int)floorf(((float)y + 0.5f) / r - 0.5f);
    int ix0 = (int)floorf(((float)x + 0.5f) / r - 0.5f);
    float* base = out + (size_t)(NCH + c) * NCELL;
#pragma unroll
    for (int a = 0; a < 2; ++a) {
        int iy = iy0 + a;
        if (iy < 0 || iy >= OHW) continue;
        float cyv = ((float)iy + 0.5f) * r - 0.5f;
        float wy = fmaxf(0.f, 1.f - fabsf(cyv - (float)y) / r) / S[iy];
#pragma unroll
        for (int b = 0; b < 2; ++b) {
            int ix = ix0 + b;
            if (ix < 0 || ix >= OHW) continue;
            float cxv = ((float)ix + 0.5f) * r - 0.5f;
            float wx = fmaxf(0.f, 1.f - fabsf(cxv - (float)x) / r) / S[ix];
            atomicAdd(base + iy * OHW + ix, e * wy * wx);
        }
    }
}

__global__ void k_mlp_fb(const float* __restrict__ scalar, const float* __restrict__ w1,
                         const float* __restrict__ b1, const float* __restrict__ w2,
                         const float* __restrict__ b2, float* __restrict__ out) {
    __shared__ float h[32];
    int j = threadIdx.x;
    if (j < 32) {
        float a = b1[j];
        for (int i = 0; i < 8; ++i) a = fmaf(scalar[i], w1[i * 32 + j], a);
        h[j] = fmaxf(a, 0.f);
    }
    __syncthreads();
    if (j < 4) {
        float a = b2[j];
        for (int i = 0; i < 32; ++i) a = fmaf(h[i], w2[i * 4 + j], a);
        out[(size_t)(NCH + SDIM) * NCELL + j] = fmaxf(a, 0.f);
    }
}

extern "C" void kernel_launch(void* const* d_in, const int* in_sizes, int n_in,
                              void* d_out, int out_size, void* d_ws, size_t ws_size,
                              hipStream_t stream) {
    const float* spatial = (const float*)d_in[0];
    const float* emb     = (const float*)d_in[1];
    const int*   loc     = (const int*)d_in[2];
    const float* scalar  = (const float*)d_in[3];
    const float* w1      = (const float*)d_in[4];
    const float* b1      = (const float*)d_in[5];
    const float* w2      = (const float*)d_in[6];
    const float* b2      = (const float*)d_in[7];
    float* out = (float*)d_out;

    int*   wsi = (int*)d_ws;
    float* wsf = (float*)d_ws;

    if (ws_size >= WS_REQ_BYTES) {
        int*   counts    = wsi + WS_COUNTS;
        int*   spill_cur = wsi + WS_SPILLCUR;
        float* invS      = wsf + WS_INVS;
        int2*  entries   = (int2*)(wsi + WS_ENTRIES);
        int2*  spill     = (int2*)(wsi + WS_SPILL);
        float* T         = wsf + WS_T;

        k_zero<<<ZERO_BLOCKS, 256, 0, stream>>>(counts, invS);
        k_phase1<<<FILL_BLOCKS + RY_BLOCKS, 128, 0, stream>>>(spatial, loc, T, counts,
                                                              entries, spill, spill_cur,
                                                              invS);
        k_phase2<<<GA_BLOCKS + RX_BLOCKS + 1, 256, 0, stream>>>(T, emb, counts, entries,
                                                                spill, spill_cur, invS,
                                                                out, scalar, w1, b1,
                                                                w2, b2);
    } else {
        float* S = wsf;
        hipMemsetAsync(d_out, 0, (size_t)out_size * sizeof(float), stream);
        k_norm_fb<<<1, 128, 0, stream>>>(S);
        k_spatial_fb<<<(NCH * NCELL + 255) / 256, 256, 0, stream>>>(spatial, S, out);
        k_scatter_fb<<<(NPTS * SDIM + 255) / 256, 256, 0, stream>>>(emb, loc, S, out);
        k_mlp_fb<<<1, 64, 0, stream>>>(scalar, w1, b1, w2, b2, out);
    }
}